// Round 1
// baseline (670.290 us; speedup 1.0000x reference)
//
#include <hip/hip_runtime.h>

#define N_NODES 50000
#define HIDDEN 128
#define NUM_GRAPHS 64
#define NUM_CLASSES 6

// ---------------- degree / norm ----------------
__global__ void init_deg(float* deg, int n) {
    int i = blockIdx.x * 256 + threadIdx.x;
    if (i < n) deg[i] = 1.0f;   // self-loop
}

__global__ void count_deg(const int* __restrict__ dst, float* deg, int e) {
    int i = blockIdx.x * 256 + threadIdx.x;
    if (i < e) atomicAdd(&deg[dst[i]], 1.0f);
}

__global__ void calc_dinv(const float* __restrict__ deg, float* dinv, int n) {
    int i = blockIdx.x * 256 + threadIdx.x;
    if (i < n) dinv[i] = rsqrtf(deg[i]);
}

// ---------------- CSR build ----------------
// single-block exclusive scan of (int)deg -> off[0..n], off[n] = total
__global__ __launch_bounds__(1024) void scan_kernel(const float* __restrict__ deg, int* off, int n) {
    __shared__ int sums[1024];
    const int t = threadIdx.x;
    const int chunk = (n + 1023) / 1024;
    const int base = t * chunk;
    int s = 0;
    for (int j = 0; j < chunk; j++) {
        int i = base + j;
        if (i < n) s += (int)deg[i];
    }
    sums[t] = s;
    __syncthreads();
    // Hillis-Steele inclusive scan
    for (int d = 1; d < 1024; d <<= 1) {
        int v = (t >= d) ? sums[t - d] : 0;
        __syncthreads();
        sums[t] += v;
        __syncthreads();
    }
    int run = (t == 0) ? 0 : sums[t - 1];
    for (int j = 0; j < chunk; j++) {
        int i = base + j;
        if (i < n) {
            off[i] = run;
            run += (int)deg[i];
        }
    }
    if (t == 1023) off[n] = sums[1023];
}

__global__ void fill_self(const float* __restrict__ dinv, const int* __restrict__ off,
                          int* cursor, int* col, float* val, int n) {
    int i = blockIdx.x * 256 + threadIdx.x;
    if (i >= n) return;
    int pos = off[i] + atomicAdd(&cursor[i], 1);
    col[pos] = i;
    float d = dinv[i];
    val[pos] = d * d;
}

__global__ void fill_edge(const int* __restrict__ src, const int* __restrict__ dst,
                          const float* __restrict__ dinv, const int* __restrict__ off,
                          int* cursor, int* col, float* val, int e) {
    int i = blockIdx.x * 256 + threadIdx.x;
    if (i >= e) return;
    int s = src[i], d = dst[i];
    int pos = off[d] + atomicAdd(&cursor[d], 1);
    col[pos] = s;
    val[pos] = dinv[s] * dinv[d];
}

// ---------------- GEMM: C[N,128] = A[N,128] @ W[128,128], f32 ----------------
__global__ __launch_bounds__(256) void gemm_f32(const float* __restrict__ A, const float* __restrict__ W,
                                                float* __restrict__ C, int n) {
    __shared__ float As[64][33];     // +1 pad
    __shared__ float Ws[32][128];
    const int tid = threadIdx.x;
    const int row0 = blockIdx.x * 64;
    const int tc = tid & 15;         // col group (8 cols)
    const int tr = tid >> 4;         // row group (4 rows)
    float acc[4][8];
#pragma unroll
    for (int i = 0; i < 4; i++)
#pragma unroll
        for (int j = 0; j < 8; j++) acc[i][j] = 0.f;

    for (int k0 = 0; k0 < 128; k0 += 32) {
#pragma unroll
        for (int i = 0; i < 2; i++) {          // A tile: 64 rows x 32 k
            int idx = tid + i * 256;           // 0..511
            int r = idx >> 3;
            int c = (idx & 7) * 4;
            int gr = row0 + r;
            float4 v = make_float4(0.f, 0.f, 0.f, 0.f);
            if (gr < n) v = *(const float4*)&A[gr * 128 + k0 + c];
            As[r][c + 0] = v.x; As[r][c + 1] = v.y; As[r][c + 2] = v.z; As[r][c + 3] = v.w;
        }
#pragma unroll
        for (int i = 0; i < 4; i++) {          // W tile: 32 k x 128 cols (contiguous)
            int idx = tid + i * 256;           // 0..1023
            int r = idx >> 5;
            int c = (idx & 31) * 4;
            *(float4*)&Ws[r][c] = *(const float4*)&W[(k0 + r) * 128 + c];
        }
        __syncthreads();
#pragma unroll
        for (int kk = 0; kk < 32; kk++) {
            float a0 = As[tr * 4 + 0][kk];
            float a1 = As[tr * 4 + 1][kk];
            float a2 = As[tr * 4 + 2][kk];
            float a3 = As[tr * 4 + 3][kk];
            float b[8];
#pragma unroll
            for (int j = 0; j < 8; j++) b[j] = Ws[kk][tc * 8 + j];
#pragma unroll
            for (int j = 0; j < 8; j++) {
                acc[0][j] += a0 * b[j];
                acc[1][j] += a1 * b[j];
                acc[2][j] += a2 * b[j];
                acc[3][j] += a3 * b[j];
            }
        }
        __syncthreads();
    }
#pragma unroll
    for (int i = 0; i < 4; i++) {
        int gr = row0 + tr * 4 + i;
        if (gr < n) {
#pragma unroll
            for (int j = 0; j < 8; j += 4) {
                *(float4*)&C[gr * 128 + tc * 8 + j] =
                    make_float4(acc[i][j], acc[i][j + 1], acc[i][j + 2], acc[i][j + 3]);
            }
        }
    }
}

// ---------------- aggregation: h[d] = relu(sum_{p} val[p]*hw[col[p]] + b) ----------------
__global__ __launch_bounds__(256) void agg_relu(const float* __restrict__ hw, const int* __restrict__ off,
                                                const int* __restrict__ col, const float* __restrict__ val,
                                                const float* __restrict__ bias, float* __restrict__ hout, int n) {
    const int wave = threadIdx.x >> 6;
    const int lane = threadIdx.x & 63;
    const int node = blockIdx.x * 4 + wave;
    if (node >= n) return;
    const int p0 = off[node], p1 = off[node + 1];
    float ax = 0.f, ay = 0.f;
    for (int p = p0; p < p1; p++) {
        int c = col[p];
        float v = val[p];
        float2 hv = *(const float2*)&hw[c * 128 + lane * 2];
        ax += v * hv.x;
        ay += v * hv.y;
    }
    float2 b = *(const float2*)&bias[lane * 2];
    float2 r;
    r.x = fmaxf(ax + b.x, 0.f);
    r.y = fmaxf(ay + b.y, 0.f);
    *(float2*)&hout[node * 128 + lane * 2] = r;
}

// ---------------- pooling (batch is sorted) ----------------
__global__ __launch_bounds__(128) void pool_kernel(const float* __restrict__ h, const int* __restrict__ batch,
                                                   float* emb, int* cnt, int n) {
    const int f = threadIdx.x;        // 0..127
    const int n0 = blockIdx.x * 64;
    const int n1 = min(n0 + 64, n);
    float s = 0.f;
    int cloc = 0;
    int curg = batch[n0];
    for (int nn = n0; nn < n1; nn++) {
        int g = batch[nn];
        if (g != curg) {
            atomicAdd(&emb[curg * HIDDEN + f], s);
            if (f == 0) atomicAdd(&cnt[curg], cloc);
            s = 0.f;
            cloc = 0;
            curg = g;
        }
        s += h[nn * HIDDEN + f];
        cloc++;
    }
    atomicAdd(&emb[curg * HIDDEN + f], s);
    if (f == 0) atomicAdd(&cnt[curg], cloc);
}

// ---------------- finalize: normalize embedding + logits ----------------
__global__ __launch_bounds__(128) void finalize_kernel(const float* __restrict__ emb, const int* __restrict__ cnt,
                                                       const float* __restrict__ linW, const float* __restrict__ linb,
                                                       float* out) {
    const int g = blockIdx.x;
    const int f = threadIdx.x;
    __shared__ float es[128];
    float c = (float)max(cnt[g], 1);
    float e = emb[g * HIDDEN + f] / c;
    out[NUM_GRAPHS * NUM_CLASSES + g * HIDDEN + f] = e;   // embedding after logits
    es[f] = e;
    __syncthreads();
    if (f < NUM_CLASSES) {
        float s = linb[f];
        for (int k = 0; k < HIDDEN; k++) s += es[k] * linW[k * NUM_CLASSES + f];
        out[g * NUM_CLASSES + f] = s;
    }
}

extern "C" void kernel_launch(void* const* d_in, const int* in_sizes, int n_in,
                              void* d_out, int out_size, void* d_ws, size_t ws_size,
                              hipStream_t stream) {
    const float* x    = (const float*)d_in[0];
    const int*   ei   = (const int*)d_in[1];
    const int*   batch= (const int*)d_in[2];
    const float* W0   = (const float*)d_in[3];
    const float* b0   = (const float*)d_in[4];
    const float* W1   = (const float*)d_in[5];
    const float* b1   = (const float*)d_in[6];
    const float* W2   = (const float*)d_in[7];
    const float* b2   = (const float*)d_in[8];
    const float* linW = (const float*)d_in[9];
    const float* linb = (const float*)d_in[10];
    float* out = (float*)d_out;

    const int N = N_NODES;
    const int E = in_sizes[1] / 2;
    const int M = E + N;
    const int* srcp = ei;
    const int* dstp = ei + E;

    // workspace layout (256B aligned slots)
    char* w = (char*)d_ws;
    size_t o = 0;
    auto alloc = [&](size_t bytes) { size_t r = o; o += (bytes + 255) & ~(size_t)255; return r; };
    int*   off_i  = (int*)  (w + alloc((size_t)(N + 1) * 4));
    int*   cursor = (int*)  (w + alloc((size_t)N * 4));
    float* deg    = (float*)(w + alloc((size_t)N * 4));
    float* dinv   = (float*)(w + alloc((size_t)N * 4));
    int*   colA   = (int*)  (w + alloc((size_t)M * 4));
    float* valA   = (float*)(w + alloc((size_t)M * 4));
    float* hw     = (float*)(w + alloc((size_t)N * HIDDEN * 4));
    float* h      = (float*)(w + alloc((size_t)N * HIDDEN * 4));
    float* emb    = (float*)(w + alloc((size_t)NUM_GRAPHS * HIDDEN * 4));
    int*   cnt    = (int*)  (w + alloc((size_t)NUM_GRAPHS * 4));

    hipMemsetAsync(cursor, 0, (size_t)N * 4, stream);
    hipMemsetAsync(emb, 0, (size_t)NUM_GRAPHS * HIDDEN * 4, stream);
    hipMemsetAsync(cnt, 0, (size_t)NUM_GRAPHS * 4, stream);

    init_deg<<<(N + 255) / 256, 256, 0, stream>>>(deg, N);
    count_deg<<<(E + 255) / 256, 256, 0, stream>>>(dstp, deg, E);
    calc_dinv<<<(N + 255) / 256, 256, 0, stream>>>(deg, dinv, N);
    scan_kernel<<<1, 1024, 0, stream>>>(deg, off_i, N);
    fill_self<<<(N + 255) / 256, 256, 0, stream>>>(dinv, off_i, cursor, colA, valA, N);
    fill_edge<<<(E + 255) / 256, 256, 0, stream>>>(srcp, dstp, dinv, off_i, cursor, colA, valA, E);

    const int gemm_grid = (N + 63) / 64;
    const int agg_grid  = (N + 3) / 4;

    gemm_f32<<<gemm_grid, 256, 0, stream>>>(x, W0, hw, N);
    agg_relu<<<agg_grid, 256, 0, stream>>>(hw, off_i, colA, valA, b0, h, N);
    gemm_f32<<<gemm_grid, 256, 0, stream>>>(h, W1, hw, N);
    agg_relu<<<agg_grid, 256, 0, stream>>>(hw, off_i, colA, valA, b1, h, N);
    gemm_f32<<<gemm_grid, 256, 0, stream>>>(h, W2, hw, N);
    agg_relu<<<agg_grid, 256, 0, stream>>>(hw, off_i, colA, valA, b2, h, N);

    pool_kernel<<<(N + 63) / 64, 128, 0, stream>>>(h, batch, emb, cnt, N);
    finalize_kernel<<<NUM_GRAPHS, 128, 0, stream>>>(emb, cnt, linW, linb, out);
}

// Round 2
// 576.146 us; speedup vs baseline: 1.1634x; 1.1634x over previous
//
#include <hip/hip_runtime.h>

#define N_NODES 50000
#define HIDDEN 128
#define NUM_GRAPHS 64
#define NUM_CLASSES 6
#define SCAN_NB ((N_NODES + 255) / 256)   // 196

// ---------------- degree (edges only; +1 self-loop added downstream) ----------------
__global__ void count_deg(const int* __restrict__ dst, int* deg, int e) {
    int i = blockIdx.x * 256 + threadIdx.x;
    if (i < e) atomicAdd(&deg[dst[i]], 1);
}

__global__ void calc_dinv(const int* __restrict__ deg, float* dinv, int n) {
    int i = blockIdx.x * 256 + threadIdx.x;
    if (i < n) dinv[i] = rsqrtf((float)(deg[i] + 1));
}

// ---------------- 3-phase scan of (deg[i]+1) -> off[0..n] ----------------
__global__ __launch_bounds__(256) void scan_b1(const int* __restrict__ deg, int* partial, int n) {
    __shared__ int red[4];
    const int t = threadIdx.x;
    const int i = blockIdx.x * 256 + t;
    int v = (i < n) ? (deg[i] + 1) : 0;
    // wave reduce
    for (int d = 32; d > 0; d >>= 1) v += __shfl_down(v, d, 64);
    if ((t & 63) == 0) red[t >> 6] = v;
    __syncthreads();
    if (t == 0) partial[blockIdx.x] = red[0] + red[1] + red[2] + red[3];
}

__global__ __launch_bounds__(256) void scan_b2(int* partial, int* off_n, int nb) {
    __shared__ int s[256];
    const int t = threadIdx.x;
    int v = (t < nb) ? partial[t] : 0;
    s[t] = v;
    __syncthreads();
    for (int d = 1; d < 256; d <<= 1) {
        int u = (t >= d) ? s[t - d] : 0;
        __syncthreads();
        s[t] += u;
        __syncthreads();
    }
    if (t < nb) partial[t] = s[t];           // inclusive
    if (t == nb - 1) *off_n = s[t];          // total -> off[n]
}

__global__ __launch_bounds__(256) void scan_b3(const int* __restrict__ deg, const int* __restrict__ partial,
                                               int* off, int n) {
    __shared__ int s[256];
    const int t = threadIdx.x;
    const int b = blockIdx.x;
    const int i = b * 256 + t;
    int v = (i < n) ? (deg[i] + 1) : 0;
    s[t] = v;
    __syncthreads();
    for (int d = 1; d < 256; d <<= 1) {
        int u = (t >= d) ? s[t - d] : 0;
        __syncthreads();
        s[t] += u;
        __syncthreads();
    }
    int base = (b == 0) ? 0 : partial[b - 1];
    if (i < n) off[i] = base + s[t] - v;      // exclusive
}

// ---------------- CSR fill ----------------
__global__ void fill_self(const float* __restrict__ dinv, const int* __restrict__ off,
                          int* cursor, int* col, float* val, int n) {
    int i = blockIdx.x * 256 + threadIdx.x;
    if (i >= n) return;
    int pos = off[i];            // self-loop deterministically first in segment
    col[pos] = i;
    float d = dinv[i];
    val[pos] = d * d;
    cursor[i] = 1;               // edges start after the self entry
}

__global__ void fill_edge(const int* __restrict__ src, const int* __restrict__ dst,
                          const float* __restrict__ dinv, const int* __restrict__ off,
                          int* cursor, int* col, float* val, int e) {
    int i = blockIdx.x * 256 + threadIdx.x;
    if (i >= e) return;
    int s = src[i], d = dst[i];
    int pos = off[d] + atomicAdd(&cursor[d], 1);
    col[pos] = s;
    val[pos] = dinv[s] * dinv[d];
}

// ---------------- GEMM: C[N,128] = A[N,128] @ W[128,128], f32 ----------------
__global__ __launch_bounds__(256) void gemm_f32(const float* __restrict__ A, const float* __restrict__ W,
                                                float* __restrict__ C, int n) {
    __shared__ float As[64][33];     // +1 pad
    __shared__ float Ws[32][128];
    const int tid = threadIdx.x;
    const int row0 = blockIdx.x * 64;
    const int tc = tid & 15;         // col group (8 cols)
    const int tr = tid >> 4;         // row group (4 rows)
    float acc[4][8];
#pragma unroll
    for (int i = 0; i < 4; i++)
#pragma unroll
        for (int j = 0; j < 8; j++) acc[i][j] = 0.f;

    for (int k0 = 0; k0 < 128; k0 += 32) {
#pragma unroll
        for (int i = 0; i < 2; i++) {          // A tile: 64 rows x 32 k
            int idx = tid + i * 256;           // 0..511
            int r = idx >> 3;
            int c = (idx & 7) * 4;
            int gr = row0 + r;
            float4 v = make_float4(0.f, 0.f, 0.f, 0.f);
            if (gr < n) v = *(const float4*)&A[gr * 128 + k0 + c];
            As[r][c + 0] = v.x; As[r][c + 1] = v.y; As[r][c + 2] = v.z; As[r][c + 3] = v.w;
        }
#pragma unroll
        for (int i = 0; i < 4; i++) {          // W tile: 32 k x 128 cols
            int idx = tid + i * 256;           // 0..1023
            int r = idx >> 5;
            int c = (idx & 31) * 4;
            *(float4*)&Ws[r][c] = *(const float4*)&W[(k0 + r) * 128 + c];
        }
        __syncthreads();
#pragma unroll
        for (int kk = 0; kk < 32; kk++) {
            float a0 = As[tr * 4 + 0][kk];
            float a1 = As[tr * 4 + 1][kk];
            float a2 = As[tr * 4 + 2][kk];
            float a3 = As[tr * 4 + 3][kk];
            float b[8];
#pragma unroll
            for (int j = 0; j < 8; j++) b[j] = Ws[kk][tc * 8 + j];
#pragma unroll
            for (int j = 0; j < 8; j++) {
                acc[0][j] += a0 * b[j];
                acc[1][j] += a1 * b[j];
                acc[2][j] += a2 * b[j];
                acc[3][j] += a3 * b[j];
            }
        }
        __syncthreads();
    }
#pragma unroll
    for (int i = 0; i < 4; i++) {
        int gr = row0 + tr * 4 + i;
        if (gr < n) {
#pragma unroll
            for (int j = 0; j < 8; j += 4) {
                *(float4*)&C[gr * 128 + tc * 8 + j] =
                    make_float4(acc[i][j], acc[i][j + 1], acc[i][j + 2], acc[i][j + 3]);
            }
        }
    }
}

// ---------------- aggregation: h[d] = relu(sum_{p} val[p]*hw[col[p]] + b) ----------------
__global__ __launch_bounds__(256) void agg_relu(const float* __restrict__ hw, const int* __restrict__ off,
                                                const int* __restrict__ col, const float* __restrict__ val,
                                                const float* __restrict__ bias, float* __restrict__ hout, int n) {
    const int wave = threadIdx.x >> 6;
    const int lane = threadIdx.x & 63;
    const int node = blockIdx.x * 4 + wave;
    if (node >= n) return;
    const int p0 = off[node], p1 = off[node + 1];
    float ax = 0.f, ay = 0.f;
    for (int p = p0; p < p1; p++) {
        int c = col[p];
        float v = val[p];
        float2 hv = *(const float2*)&hw[c * 128 + lane * 2];
        ax += v * hv.x;
        ay += v * hv.y;
    }
    float2 b = *(const float2*)&bias[lane * 2];
    float2 r;
    r.x = fmaxf(ax + b.x, 0.f);
    r.y = fmaxf(ay + b.y, 0.f);
    *(float2*)&hout[node * 128 + lane * 2] = r;
}

// ---------------- pooling (batch is sorted) ----------------
__global__ __launch_bounds__(128) void pool_kernel(const float* __restrict__ h, const int* __restrict__ batch,
                                                   float* emb, int* cnt, int n) {
    const int f = threadIdx.x;        // 0..127
    const int n0 = blockIdx.x * 64;
    const int n1 = min(n0 + 64, n);
    float s = 0.f;
    int cloc = 0;
    int curg = batch[n0];
    for (int nn = n0; nn < n1; nn++) {
        int g = batch[nn];
        if (g != curg) {
            atomicAdd(&emb[curg * HIDDEN + f], s);
            if (f == 0) atomicAdd(&cnt[curg], cloc);
            s = 0.f;
            cloc = 0;
            curg = g;
        }
        s += h[nn * HIDDEN + f];
        cloc++;
    }
    atomicAdd(&emb[curg * HIDDEN + f], s);
    if (f == 0) atomicAdd(&cnt[curg], cloc);
}

// ---------------- finalize ----------------
__global__ __launch_bounds__(128) void finalize_kernel(const float* __restrict__ emb, const int* __restrict__ cnt,
                                                       const float* __restrict__ linW, const float* __restrict__ linb,
                                                       float* out) {
    const int g = blockIdx.x;
    const int f = threadIdx.x;
    __shared__ float es[128];
    float c = (float)max(cnt[g], 1);
    float e = emb[g * HIDDEN + f] / c;
    out[NUM_GRAPHS * NUM_CLASSES + g * HIDDEN + f] = e;
    es[f] = e;
    __syncthreads();
    if (f < NUM_CLASSES) {
        float s = linb[f];
        for (int k = 0; k < HIDDEN; k++) s += es[k] * linW[k * NUM_CLASSES + f];
        out[g * NUM_CLASSES + f] = s;
    }
}

extern "C" void kernel_launch(void* const* d_in, const int* in_sizes, int n_in,
                              void* d_out, int out_size, void* d_ws, size_t ws_size,
                              hipStream_t stream) {
    const float* x    = (const float*)d_in[0];
    const int*   ei   = (const int*)d_in[1];
    const int*   batch= (const int*)d_in[2];
    const float* W0   = (const float*)d_in[3];
    const float* b0   = (const float*)d_in[4];
    const float* W1   = (const float*)d_in[5];
    const float* b1   = (const float*)d_in[6];
    const float* W2   = (const float*)d_in[7];
    const float* b2   = (const float*)d_in[8];
    const float* linW = (const float*)d_in[9];
    const float* linb = (const float*)d_in[10];
    float* out = (float*)d_out;

    const int N = N_NODES;
    const int E = in_sizes[1] / 2;
    const int M = E + N;
    const int* srcp = ei;
    const int* dstp = ei + E;

    char* w = (char*)d_ws;
    size_t o = 0;
    auto alloc = [&](size_t bytes) { size_t r = o; o += (bytes + 255) & ~(size_t)255; return r; };
    int*   off_i   = (int*)  (w + alloc((size_t)(N + 1) * 4));
    int*   cursor  = (int*)  (w + alloc((size_t)N * 4));
    int*   deg     = (int*)  (w + alloc((size_t)N * 4));
    float* dinv    = (float*)(w + alloc((size_t)N * 4));
    int*   partial = (int*)  (w + alloc((size_t)SCAN_NB * 4));
    int*   colA    = (int*)  (w + alloc((size_t)M * 4));
    float* valA    = (float*)(w + alloc((size_t)M * 4));
    float* hw      = (float*)(w + alloc((size_t)N * HIDDEN * 4));
    float* h       = (float*)(w + alloc((size_t)N * HIDDEN * 4));
    float* emb     = (float*)(w + alloc((size_t)NUM_GRAPHS * HIDDEN * 4));
    int*   cnt     = (int*)  (w + alloc((size_t)NUM_GRAPHS * 4));

    hipMemsetAsync(deg, 0, (size_t)N * 4, stream);
    hipMemsetAsync(emb, 0, (size_t)NUM_GRAPHS * HIDDEN * 4, stream);
    hipMemsetAsync(cnt, 0, (size_t)NUM_GRAPHS * 4, stream);

    count_deg<<<(E + 255) / 256, 256, 0, stream>>>(dstp, deg, E);
    calc_dinv<<<(N + 255) / 256, 256, 0, stream>>>(deg, dinv, N);

    scan_b1<<<SCAN_NB, 256, 0, stream>>>(deg, partial, N);
    scan_b2<<<1, 256, 0, stream>>>(partial, off_i + N, SCAN_NB);
    scan_b3<<<SCAN_NB, 256, 0, stream>>>(deg, partial, off_i, N);

    fill_self<<<(N + 255) / 256, 256, 0, stream>>>(dinv, off_i, cursor, colA, valA, N);
    fill_edge<<<(E + 255) / 256, 256, 0, stream>>>(srcp, dstp, dinv, off_i, cursor, colA, valA, E);

    const int gemm_grid = (N + 63) / 64;
    const int agg_grid  = (N + 3) / 4;

    gemm_f32<<<gemm_grid, 256, 0, stream>>>(x, W0, hw, N);
    agg_relu<<<agg_grid, 256, 0, stream>>>(hw, off_i, colA, valA, b0, h, N);
    gemm_f32<<<gemm_grid, 256, 0, stream>>>(h, W1, hw, N);
    agg_relu<<<agg_grid, 256, 0, stream>>>(hw, off_i, colA, valA, b1, h, N);
    gemm_f32<<<gemm_grid, 256, 0, stream>>>(h, W2, hw, N);
    agg_relu<<<agg_grid, 256, 0, stream>>>(hw, off_i, colA, valA, b2, h, N);

    pool_kernel<<<(N + 63) / 64, 128, 0, stream>>>(h, batch, emb, cnt, N);
    finalize_kernel<<<NUM_GRAPHS, 128, 0, stream>>>(emb, cnt, linW, linb, out);
}

// Round 3
// 506.936 us; speedup vs baseline: 1.3222x; 1.1365x over previous
//
#include <hip/hip_runtime.h>

#define N_NODES 50000
#define HIDDEN 128
#define NUM_GRAPHS 64
#define NUM_CLASSES 6
#define SCAN_NB ((N_NODES + 255) / 256)   // 196
#define N_PAD 50048                       // N rounded up to 64

typedef __attribute__((ext_vector_type(8))) short short8;
typedef __attribute__((ext_vector_type(4))) float float4v;

__device__ __forceinline__ float b2f(unsigned short u) {
    return __uint_as_float(((unsigned)u) << 16);
}
__device__ __forceinline__ unsigned short f2b(float f) {
    unsigned u = __float_as_uint(f);
    return (unsigned short)((u + 0x7FFFu + ((u >> 16) & 1u)) >> 16);
}

// ---------------- degree ----------------
__global__ void count_deg(const int* __restrict__ dst, int* deg, int e) {
    int i = blockIdx.x * 256 + threadIdx.x;
    if (i < e) atomicAdd(&deg[dst[i]], 1);
}

__global__ void calc_dinv(const int* __restrict__ deg, float* dinv, int n) {
    int i = blockIdx.x * 256 + threadIdx.x;
    if (i < n) dinv[i] = rsqrtf((float)(deg[i] + 1));
}

// ---------------- 3-phase scan of (deg[i]+1) -> off[0..n] ----------------
__global__ __launch_bounds__(256) void scan_b1(const int* __restrict__ deg, int* partial, int n) {
    __shared__ int red[4];
    const int t = threadIdx.x;
    const int i = blockIdx.x * 256 + t;
    int v = (i < n) ? (deg[i] + 1) : 0;
    for (int d = 32; d > 0; d >>= 1) v += __shfl_down(v, d, 64);
    if ((t & 63) == 0) red[t >> 6] = v;
    __syncthreads();
    if (t == 0) partial[blockIdx.x] = red[0] + red[1] + red[2] + red[3];
}

__global__ __launch_bounds__(256) void scan_b2(int* partial, int* off_n, int nb) {
    __shared__ int s[256];
    const int t = threadIdx.x;
    int v = (t < nb) ? partial[t] : 0;
    s[t] = v;
    __syncthreads();
    for (int d = 1; d < 256; d <<= 1) {
        int u = (t >= d) ? s[t - d] : 0;
        __syncthreads();
        s[t] += u;
        __syncthreads();
    }
    if (t < nb) partial[t] = s[t];
    if (t == nb - 1) *off_n = s[t];
}

__global__ __launch_bounds__(256) void scan_b3(const int* __restrict__ deg, const int* __restrict__ partial,
                                               int* off, int n) {
    __shared__ int s[256];
    const int t = threadIdx.x;
    const int b = blockIdx.x;
    const int i = b * 256 + t;
    int v = (i < n) ? (deg[i] + 1) : 0;
    s[t] = v;
    __syncthreads();
    for (int d = 1; d < 256; d <<= 1) {
        int u = (t >= d) ? s[t - d] : 0;
        __syncthreads();
        s[t] += u;
        __syncthreads();
    }
    int base = (b == 0) ? 0 : partial[b - 1];
    if (i < n) off[i] = base + s[t] - v;
}

// ---------------- CSR fill ----------------
__global__ void fill_self(const float* __restrict__ dinv, const int* __restrict__ off,
                          int* cursor, int* col, float* val, int n) {
    int i = blockIdx.x * 256 + threadIdx.x;
    if (i >= n) return;
    int pos = off[i];
    col[pos] = i;
    float d = dinv[i];
    val[pos] = d * d;
    cursor[i] = 1;
}

__global__ void fill_edge(const int* __restrict__ src, const int* __restrict__ dst,
                          const float* __restrict__ dinv, const int* __restrict__ off,
                          int* cursor, int* col, float* val, int e) {
    int i = blockIdx.x * 256 + threadIdx.x;
    if (i >= e) return;
    int s = src[i], d = dst[i];
    int pos = off[d] + atomicAdd(&cursor[d], 1);
    col[pos] = s;
    val[pos] = dinv[s] * dinv[d];
}

// ---------------- cast x f32 -> bf16 ----------------
__global__ void cast_x(const float* __restrict__ x, unsigned short* __restrict__ xb, int total) {
    int i = (blockIdx.x * 256 + threadIdx.x) * 4;
    if (i >= total) return;
    float4 v = *(const float4*)&x[i];
    ushort4 o;
    o.x = f2b(v.x); o.y = f2b(v.y); o.z = f2b(v.z); o.w = f2b(v.w);
    *(ushort4*)&xb[i] = o;
}

// ---------------- convert W0/W1/W2 into MFMA-B fragment order, bf16 ----------------
// layout per weight: frag f = ki*8+nt (ki=k-block of 32, nt=col tile of 16);
// element ((f*64)+lane)*8+j  <-  W[ki*32 + (lane>>4)*8 + j][nt*16 + (lane&15)]
__global__ void conv_w(const float* __restrict__ W0, const float* __restrict__ W1,
                       const float* __restrict__ W2, unsigned short* __restrict__ wb) {
    int i = blockIdx.x * 256 + threadIdx.x;
    if (i >= 3 * 16384) return;
    int wsel = i >> 14;
    int r = i & 16383;
    int j = r & 7;
    int lane = (r >> 3) & 63;
    int f = r >> 9;               // 0..31
    int ki = f >> 3, nt = f & 7;
    int k = ki * 32 + (lane >> 4) * 8 + j;
    int c = nt * 16 + (lane & 15);
    const float* W = (wsel == 0) ? W0 : ((wsel == 1) ? W1 : W2);
    wb[i] = f2b(W[k * 128 + c]);
}

// ---------------- aggregation: t[d] = sum_p val[p]*h[col[p]]  (bf16 in/out, f32 accum) ----------------
__global__ __launch_bounds__(256) void agg_bf16(const unsigned short* __restrict__ hb, const int* __restrict__ off,
                                                const int* __restrict__ col, const float* __restrict__ val,
                                                unsigned short* __restrict__ tb, int n) {
    const int wave = threadIdx.x >> 6;
    const int lane = threadIdx.x & 63;
    const int node = blockIdx.x * 4 + wave;
    if (node >= n) return;
    const int p0 = off[node], p1 = off[node + 1];
    float ax = 0.f, ay = 0.f;
    for (int p = p0; p < p1; p++) {
        int c = col[p];
        float v = val[p];
        ushort2 u = *(const ushort2*)&hb[c * 128 + lane * 2];
        ax += v * b2f(u.x);
        ay += v * b2f(u.y);
    }
    ushort2 o;
    o.x = f2b(ax); o.y = f2b(ay);
    *(ushort2*)&tb[node * 128 + lane * 2] = o;
}

// ---------------- GEMM: h = relu(t @ W + b), bf16 MFMA, f32 accum ----------------
__global__ __launch_bounds__(256) void gemm_mfma(const unsigned short* __restrict__ tb,
                                                 const unsigned short* __restrict__ wb,
                                                 const float* __restrict__ bias,
                                                 unsigned short* __restrict__ hout, int n) {
    const int lane = threadIdx.x & 63;
    const int wave = threadIdx.x >> 6;
    const int r0 = blockIdx.x * 64 + wave * 16;
    const int m = lane & 15;
    const int quad = lane >> 4;
    const short* A = (const short*)tb;
    const short* B = (const short*)wb;

    float4v acc[8];
#pragma unroll
    for (int nt = 0; nt < 8; nt++) acc[nt] = (float4v){0.f, 0.f, 0.f, 0.f};

#pragma unroll
    for (int ki = 0; ki < 4; ki++) {
        short8 a = *(const short8*)&A[(r0 + m) * 128 + ki * 32 + quad * 8];
#pragma unroll
        for (int nt = 0; nt < 8; nt++) {
            short8 b = *(const short8*)&B[((ki * 8 + nt) * 64 + lane) * 8];
            acc[nt] = __builtin_amdgcn_mfma_f32_16x16x32_bf16(a, b, acc[nt], 0, 0, 0);
        }
    }

#pragma unroll
    for (int nt = 0; nt < 8; nt++) {
        int c = nt * 16 + m;
        float bv = bias[c];
#pragma unroll
        for (int reg = 0; reg < 4; reg++) {
            int row = r0 + quad * 4 + reg;
            if (row < n) {
                float v = fmaxf(acc[nt][reg] + bv, 0.f);
                hout[row * 128 + c] = f2b(v);
            }
        }
    }
}

// ---------------- pooling (batch sorted), bf16 input ----------------
__global__ __launch_bounds__(128) void pool_kernel(const unsigned short* __restrict__ h, const int* __restrict__ batch,
                                                   float* emb, int* cnt, int n) {
    const int f = threadIdx.x;        // 0..127
    const int n0 = blockIdx.x * 64;
    const int n1 = min(n0 + 64, n);
    float s = 0.f;
    int cloc = 0;
    int curg = batch[n0];
    for (int nn = n0; nn < n1; nn++) {
        int g = batch[nn];
        if (g != curg) {
            atomicAdd(&emb[curg * HIDDEN + f], s);
            if (f == 0) atomicAdd(&cnt[curg], cloc);
            s = 0.f;
            cloc = 0;
            curg = g;
        }
        s += b2f(h[nn * HIDDEN + f]);
        cloc++;
    }
    atomicAdd(&emb[curg * HIDDEN + f], s);
    if (f == 0) atomicAdd(&cnt[curg], cloc);
}

// ---------------- finalize ----------------
__global__ __launch_bounds__(128) void finalize_kernel(const float* __restrict__ emb, const int* __restrict__ cnt,
                                                       const float* __restrict__ linW, const float* __restrict__ linb,
                                                       float* out) {
    const int g = blockIdx.x;
    const int f = threadIdx.x;
    __shared__ float es[128];
    float c = (float)max(cnt[g], 1);
    float e = emb[g * HIDDEN + f] / c;
    out[NUM_GRAPHS * NUM_CLASSES + g * HIDDEN + f] = e;
    es[f] = e;
    __syncthreads();
    if (f < NUM_CLASSES) {
        float s = linb[f];
        for (int k = 0; k < HIDDEN; k++) s += es[k] * linW[k * NUM_CLASSES + f];
        out[g * NUM_CLASSES + f] = s;
    }
}

extern "C" void kernel_launch(void* const* d_in, const int* in_sizes, int n_in,
                              void* d_out, int out_size, void* d_ws, size_t ws_size,
                              hipStream_t stream) {
    const float* x    = (const float*)d_in[0];
    const int*   ei   = (const int*)d_in[1];
    const int*   batch= (const int*)d_in[2];
    const float* W0   = (const float*)d_in[3];
    const float* b0   = (const float*)d_in[4];
    const float* W1   = (const float*)d_in[5];
    const float* b1   = (const float*)d_in[6];
    const float* W2   = (const float*)d_in[7];
    const float* b2   = (const float*)d_in[8];
    const float* linW = (const float*)d_in[9];
    const float* linb = (const float*)d_in[10];
    float* out = (float*)d_out;

    const int N = N_NODES;
    const int E = in_sizes[1] / 2;
    const int M = E + N;
    const int* srcp = ei;
    const int* dstp = ei + E;

    char* w = (char*)d_ws;
    size_t o = 0;
    auto alloc = [&](size_t bytes) { size_t r = o; o += (bytes + 255) & ~(size_t)255; return r; };
    int*            off_i   = (int*)           (w + alloc((size_t)(N + 1) * 4));
    int*            cursor  = (int*)           (w + alloc((size_t)N * 4));
    int*            deg     = (int*)           (w + alloc((size_t)N * 4));
    float*          dinv    = (float*)         (w + alloc((size_t)N * 4));
    int*            partial = (int*)           (w + alloc((size_t)SCAN_NB * 4));
    int*            colA    = (int*)           (w + alloc((size_t)M * 4));
    float*          valA    = (float*)         (w + alloc((size_t)M * 4));
    unsigned short* xb      = (unsigned short*)(w + alloc((size_t)N_PAD * HIDDEN * 2));
    unsigned short* tb      = (unsigned short*)(w + alloc((size_t)N_PAD * HIDDEN * 2));
    unsigned short* hb      = (unsigned short*)(w + alloc((size_t)N_PAD * HIDDEN * 2));
    unsigned short* wb      = (unsigned short*)(w + alloc((size_t)3 * 16384 * 2));
    float*          emb     = (float*)         (w + alloc((size_t)NUM_GRAPHS * HIDDEN * 4));
    int*            cnt     = (int*)           (w + alloc((size_t)NUM_GRAPHS * 4));

    hipMemsetAsync(deg, 0, (size_t)N * 4, stream);
    hipMemsetAsync(emb, 0, (size_t)NUM_GRAPHS * HIDDEN * 4, stream);
    hipMemsetAsync(cnt, 0, (size_t)NUM_GRAPHS * 4, stream);

    cast_x<<<(N * HIDDEN / 4 + 255) / 256, 256, 0, stream>>>(x, xb, N * HIDDEN);
    conv_w<<<(3 * 16384 + 255) / 256, 256, 0, stream>>>(W0, W1, W2, wb);

    count_deg<<<(E + 255) / 256, 256, 0, stream>>>(dstp, deg, E);
    calc_dinv<<<(N + 255) / 256, 256, 0, stream>>>(deg, dinv, N);

    scan_b1<<<SCAN_NB, 256, 0, stream>>>(deg, partial, N);
    scan_b2<<<1, 256, 0, stream>>>(partial, off_i + N, SCAN_NB);
    scan_b3<<<SCAN_NB, 256, 0, stream>>>(deg, partial, off_i, N);

    fill_self<<<(N + 255) / 256, 256, 0, stream>>>(dinv, off_i, cursor, colA, valA, N);
    fill_edge<<<(E + 255) / 256, 256, 0, stream>>>(srcp, dstp, dinv, off_i, cursor, colA, valA, E);

    const int gemm_grid = (N + 63) / 64;   // 782
    const int agg_grid  = (N + 3) / 4;     // 12500

    // layer 0: t = A @ x ; h = relu(t @ W0 + b0)
    agg_bf16<<<agg_grid, 256, 0, stream>>>(xb, off_i, colA, valA, tb, N);
    gemm_mfma<<<gemm_grid, 256, 0, stream>>>(tb, wb + 0 * 16384, b0, hb, N);
    // layer 1
    agg_bf16<<<agg_grid, 256, 0, stream>>>(hb, off_i, colA, valA, tb, N);
    gemm_mfma<<<gemm_grid, 256, 0, stream>>>(tb, wb + 1 * 16384, b1, hb, N);
    // layer 2
    agg_bf16<<<agg_grid, 256, 0, stream>>>(hb, off_i, colA, valA, tb, N);
    gemm_mfma<<<gemm_grid, 256, 0, stream>>>(tb, wb + 2 * 16384, b2, hb, N);

    pool_kernel<<<(N + 63) / 64, 128, 0, stream>>>(hb, batch, emb, cnt, N);
    finalize_kernel<<<NUM_GRAPHS, 128, 0, stream>>>(emb, cnt, linW, linb, out);
}

// Round 4
// 359.357 us; speedup vs baseline: 1.8652x; 1.4107x over previous
//
#include <hip/hip_runtime.h>

#define N_NODES 50000
#define HIDDEN 128
#define NUM_GRAPHS 64
#define NUM_CLASSES 6
#define SCAN_NB ((N_NODES + 255) / 256)   // 196
#define N_PAD 50048                       // N rounded up to 64

typedef __attribute__((ext_vector_type(8))) short short8;
typedef __attribute__((ext_vector_type(4))) float float4v;

__device__ __forceinline__ float b2f(unsigned short u) {
    return __uint_as_float(((unsigned)u) << 16);
}
__device__ __forceinline__ unsigned short f2b(float f) {
    unsigned u = __float_as_uint(f);
    return (unsigned short)((u + 0x7FFFu + ((u >> 16) & 1u)) >> 16);
}

// ---------------- degree ----------------
__global__ void count_deg(const int* __restrict__ dst, int* deg, int e) {
    int i = blockIdx.x * 256 + threadIdx.x;
    if (i < e) atomicAdd(&deg[dst[i]], 1);
}

__global__ void calc_dinv(const int* __restrict__ deg, float* dinv, int n) {
    int i = blockIdx.x * 256 + threadIdx.x;
    if (i < n) dinv[i] = rsqrtf((float)(deg[i] + 1));
}

// ---------------- 3-phase scan of (deg[i]+1) -> off[0..n] ----------------
__global__ __launch_bounds__(256) void scan_b1(const int* __restrict__ deg, int* partial, int n) {
    __shared__ int red[4];
    const int t = threadIdx.x;
    const int i = blockIdx.x * 256 + t;
    int v = (i < n) ? (deg[i] + 1) : 0;
    for (int d = 32; d > 0; d >>= 1) v += __shfl_down(v, d, 64);
    if ((t & 63) == 0) red[t >> 6] = v;
    __syncthreads();
    if (t == 0) partial[blockIdx.x] = red[0] + red[1] + red[2] + red[3];
}

__global__ __launch_bounds__(256) void scan_b2(int* partial, int* off_n, int nb) {
    __shared__ int s[256];
    const int t = threadIdx.x;
    int v = (t < nb) ? partial[t] : 0;
    s[t] = v;
    __syncthreads();
    for (int d = 1; d < 256; d <<= 1) {
        int u = (t >= d) ? s[t - d] : 0;
        __syncthreads();
        s[t] += u;
        __syncthreads();
    }
    if (t < nb) partial[t] = s[t];
    if (t == nb - 1) *off_n = s[t];
}

__global__ __launch_bounds__(256) void scan_b3(const int* __restrict__ deg, const int* __restrict__ partial,
                                               int* off, int n) {
    __shared__ int s[256];
    const int t = threadIdx.x;
    const int b = blockIdx.x;
    const int i = b * 256 + t;
    int v = (i < n) ? (deg[i] + 1) : 0;
    s[t] = v;
    __syncthreads();
    for (int d = 1; d < 256; d <<= 1) {
        int u = (t >= d) ? s[t - d] : 0;
        __syncthreads();
        s[t] += u;
        __syncthreads();
    }
    int base = (b == 0) ? 0 : partial[b - 1];
    if (i < n) off[i] = base + s[t] - v;
}

// ---------------- CSR fill ----------------
__global__ void fill_self(const float* __restrict__ dinv, const int* __restrict__ off,
                          int* cursor, int* col, float* val, int n) {
    int i = blockIdx.x * 256 + threadIdx.x;
    if (i >= n) return;
    int pos = off[i];
    col[pos] = i;
    float d = dinv[i];
    val[pos] = d * d;
    cursor[i] = 1;
}

__global__ void fill_edge(const int* __restrict__ src, const int* __restrict__ dst,
                          const float* __restrict__ dinv, const int* __restrict__ off,
                          int* cursor, int* col, float* val, int e) {
    int i = blockIdx.x * 256 + threadIdx.x;
    if (i >= e) return;
    int s = src[i], d = dst[i];
    int pos = off[d] + atomicAdd(&cursor[d], 1);
    col[pos] = s;
    val[pos] = dinv[s] * dinv[d];
}

// ---------------- cast x f32 -> bf16 ----------------
__global__ void cast_x(const float* __restrict__ x, unsigned short* __restrict__ xb, int total) {
    int i = (blockIdx.x * 256 + threadIdx.x) * 4;
    if (i >= total) return;
    float4 v = *(const float4*)&x[i];
    ushort4 o;
    o.x = f2b(v.x); o.y = f2b(v.y); o.z = f2b(v.z); o.w = f2b(v.w);
    *(ushort4*)&xb[i] = o;
}

// ---------------- convert W0/W1/W2 into MFMA-B fragment order, bf16 ----------------
__global__ void conv_w(const float* __restrict__ W0, const float* __restrict__ W1,
                       const float* __restrict__ W2, unsigned short* __restrict__ wb) {
    int i = blockIdx.x * 256 + threadIdx.x;
    if (i >= 3 * 16384) return;
    int wsel = i >> 14;
    int r = i & 16383;
    int j = r & 7;
    int lane = (r >> 3) & 63;
    int f = r >> 9;               // 0..31
    int ki = f >> 3, nt = f & 7;
    int k = ki * 32 + (lane >> 4) * 8 + j;
    int c = nt * 16 + (lane & 15);
    const float* W = (wsel == 0) ? W0 : ((wsel == 1) ? W1 : W2);
    wb[i] = f2b(W[k * 128 + c]);
}

// ---------------- aggregation: t[d] = sum_p val[p]*h[col[p]] ----------------
// wave per node; col/val batch-loaded once; 4 lane-groups x 16B dwordx4 gathers (4 rows in flight)
__global__ __launch_bounds__(256) void agg_bf16(const unsigned short* __restrict__ hb, const int* __restrict__ off,
                                                const int* __restrict__ col, const float* __restrict__ val,
                                                unsigned short* __restrict__ tb, int n) {
    const int wave = threadIdx.x >> 6;
    const int lane = threadIdx.x & 63;
    const int node = blockIdx.x * 4 + wave;
    if (node >= n) return;
    const int p0 = off[node], p1 = off[node + 1];
    const int grp = lane >> 4;      // 0..3: which edge in the chunk
    const int fl = lane & 15;       // feature sub-lane: features fl*8 .. fl*8+7

    float acc[8];
#pragma unroll
    for (int j = 0; j < 8; j++) acc[j] = 0.f;

    for (int base = p0; base < p1; base += 64) {
        const int nb = min(64, p1 - base);
        int myc = 0;
        float myv = 0.f;
        if (lane < nb) {
            myc = col[base + lane];
            myv = val[base + lane];
        }
        for (int c0 = 0; c0 < nb; c0 += 4) {
            const int e = c0 + grp;
            const int cc = __shfl(myc, e, 64);
            const float vv = __shfl(myv, e, 64);
            if (e < nb) {
                short8 u = *(const short8*)&hb[cc * 128 + fl * 8];
#pragma unroll
                for (int j = 0; j < 8; j++) acc[j] += vv * b2f((unsigned short)u[j]);
            }
        }
    }

    // cross-group reduce (groups hold disjoint edge subsets of same features)
#pragma unroll
    for (int j = 0; j < 8; j++) {
        acc[j] += __shfl_xor(acc[j], 16, 64);
        acc[j] += __shfl_xor(acc[j], 32, 64);
    }

    if (grp == 0) {
        short8 o;
#pragma unroll
        for (int j = 0; j < 8; j++) o[j] = (short)f2b(acc[j]);
        *(short8*)&tb[node * 128 + fl * 8] = o;
    }
}

// ---------------- GEMM: h = relu(t @ W + b), bf16 MFMA, f32 accum ----------------
__global__ __launch_bounds__(256) void gemm_mfma(const unsigned short* __restrict__ tb,
                                                 const unsigned short* __restrict__ wb,
                                                 const float* __restrict__ bias,
                                                 unsigned short* __restrict__ hout, int n) {
    const int lane = threadIdx.x & 63;
    const int wave = threadIdx.x >> 6;
    const int r0 = blockIdx.x * 64 + wave * 16;
    const int m = lane & 15;
    const int quad = lane >> 4;
    const short* A = (const short*)tb;
    const short* B = (const short*)wb;

    float4v acc[8];
#pragma unroll
    for (int nt = 0; nt < 8; nt++) acc[nt] = (float4v){0.f, 0.f, 0.f, 0.f};

#pragma unroll
    for (int ki = 0; ki < 4; ki++) {
        short8 a = *(const short8*)&A[(r0 + m) * 128 + ki * 32 + quad * 8];
#pragma unroll
        for (int nt = 0; nt < 8; nt++) {
            short8 b = *(const short8*)&B[((ki * 8 + nt) * 64 + lane) * 8];
            acc[nt] = __builtin_amdgcn_mfma_f32_16x16x32_bf16(a, b, acc[nt], 0, 0, 0);
        }
    }

#pragma unroll
    for (int nt = 0; nt < 8; nt++) {
        int c = nt * 16 + m;
        float bv = bias[c];
#pragma unroll
        for (int reg = 0; reg < 4; reg++) {
            int row = r0 + quad * 4 + reg;
            if (row < n) {
                float v = fmaxf(acc[nt][reg] + bv, 0.f);
                hout[row * 128 + c] = f2b(v);
            }
        }
    }
}

// ---------------- pooling (batch sorted), bf16 input ----------------
__global__ __launch_bounds__(128) void pool_kernel(const unsigned short* __restrict__ h, const int* __restrict__ batch,
                                                   float* emb, int* cnt, int n) {
    const int f = threadIdx.x;        // 0..127
    const int n0 = blockIdx.x * 64;
    const int n1 = min(n0 + 64, n);
    float s = 0.f;
    int cloc = 0;
    int curg = batch[n0];
    for (int nn = n0; nn < n1; nn++) {
        int g = batch[nn];
        if (g != curg) {
            atomicAdd(&emb[curg * HIDDEN + f], s);
            if (f == 0) atomicAdd(&cnt[curg], cloc);
            s = 0.f;
            cloc = 0;
            curg = g;
        }
        s += b2f(h[nn * HIDDEN + f]);
        cloc++;
    }
    atomicAdd(&emb[curg * HIDDEN + f], s);
    if (f == 0) atomicAdd(&cnt[curg], cloc);
}

// ---------------- finalize ----------------
__global__ __launch_bounds__(128) void finalize_kernel(const float* __restrict__ emb, const int* __restrict__ cnt,
                                                       const float* __restrict__ linW, const float* __restrict__ linb,
                                                       float* out) {
    const int g = blockIdx.x;
    const int f = threadIdx.x;
    __shared__ float es[128];
    float c = (float)max(cnt[g], 1);
    float e = emb[g * HIDDEN + f] / c;
    out[NUM_GRAPHS * NUM_CLASSES + g * HIDDEN + f] = e;
    es[f] = e;
    __syncthreads();
    if (f < NUM_CLASSES) {
        float s = linb[f];
        for (int k = 0; k < HIDDEN; k++) s += es[k] * linW[k * NUM_CLASSES + f];
        out[g * NUM_CLASSES + f] = s;
    }
}

extern "C" void kernel_launch(void* const* d_in, const int* in_sizes, int n_in,
                              void* d_out, int out_size, void* d_ws, size_t ws_size,
                              hipStream_t stream) {
    const float* x    = (const float*)d_in[0];
    const int*   ei   = (const int*)d_in[1];
    const int*   batch= (const int*)d_in[2];
    const float* W0   = (const float*)d_in[3];
    const float* b0   = (const float*)d_in[4];
    const float* W1   = (const float*)d_in[5];
    const float* b1   = (const float*)d_in[6];
    const float* W2   = (const float*)d_in[7];
    const float* b2   = (const float*)d_in[8];
    const float* linW = (const float*)d_in[9];
    const float* linb = (const float*)d_in[10];
    float* out = (float*)d_out;

    const int N = N_NODES;
    const int E = in_sizes[1] / 2;
    const int M = E + N;
    const int* srcp = ei;
    const int* dstp = ei + E;

    char* w = (char*)d_ws;
    size_t o = 0;
    auto alloc = [&](size_t bytes) { size_t r = o; o += (bytes + 255) & ~(size_t)255; return r; };
    int*            off_i   = (int*)           (w + alloc((size_t)(N + 1) * 4));
    int*            cursor  = (int*)           (w + alloc((size_t)N * 4));
    int*            deg     = (int*)           (w + alloc((size_t)N * 4));
    float*          dinv    = (float*)         (w + alloc((size_t)N * 4));
    int*            partial = (int*)           (w + alloc((size_t)SCAN_NB * 4));
    int*            colA    = (int*)           (w + alloc((size_t)M * 4));
    float*          valA    = (float*)         (w + alloc((size_t)M * 4));
    unsigned short* xb      = (unsigned short*)(w + alloc((size_t)N_PAD * HIDDEN * 2));
    unsigned short* tb      = (unsigned short*)(w + alloc((size_t)N_PAD * HIDDEN * 2));
    unsigned short* hb      = (unsigned short*)(w + alloc((size_t)N_PAD * HIDDEN * 2));
    unsigned short* wb      = (unsigned short*)(w + alloc((size_t)3 * 16384 * 2));
    float*          emb     = (float*)         (w + alloc((size_t)NUM_GRAPHS * HIDDEN * 4));
    int*            cnt     = (int*)           (w + alloc((size_t)NUM_GRAPHS * 4));

    hipMemsetAsync(deg, 0, (size_t)N * 4, stream);
    hipMemsetAsync(emb, 0, (size_t)NUM_GRAPHS * HIDDEN * 4, stream);
    hipMemsetAsync(cnt, 0, (size_t)NUM_GRAPHS * 4, stream);

    cast_x<<<(N * HIDDEN / 4 + 255) / 256, 256, 0, stream>>>(x, xb, N * HIDDEN);
    conv_w<<<(3 * 16384 + 255) / 256, 256, 0, stream>>>(W0, W1, W2, wb);

    count_deg<<<(E + 255) / 256, 256, 0, stream>>>(dstp, deg, E);
    calc_dinv<<<(N + 255) / 256, 256, 0, stream>>>(deg, dinv, N);

    scan_b1<<<SCAN_NB, 256, 0, stream>>>(deg, partial, N);
    scan_b2<<<1, 256, 0, stream>>>(partial, off_i + N, SCAN_NB);
    scan_b3<<<SCAN_NB, 256, 0, stream>>>(deg, partial, off_i, N);

    fill_self<<<(N + 255) / 256, 256, 0, stream>>>(dinv, off_i, cursor, colA, valA, N);
    fill_edge<<<(E + 255) / 256, 256, 0, stream>>>(srcp, dstp, dinv, off_i, cursor, colA, valA, E);

    const int gemm_grid = (N + 63) / 64;   // 782
    const int agg_grid  = (N + 3) / 4;     // 12500

    agg_bf16<<<agg_grid, 256, 0, stream>>>(xb, off_i, colA, valA, tb, N);
    gemm_mfma<<<gemm_grid, 256, 0, stream>>>(tb, wb + 0 * 16384, b0, hb, N);
    agg_bf16<<<agg_grid, 256, 0, stream>>>(hb, off_i, colA, valA, tb, N);
    gemm_mfma<<<gemm_grid, 256, 0, stream>>>(tb, wb + 1 * 16384, b1, hb, N);
    agg_bf16<<<agg_grid, 256, 0, stream>>>(hb, off_i, colA, valA, tb, N);
    gemm_mfma<<<gemm_grid, 256, 0, stream>>>(tb, wb + 2 * 16384, b2, hb, N);

    pool_kernel<<<(N + 63) / 64, 128, 0, stream>>>(hb, batch, emb, cnt, N);
    finalize_kernel<<<NUM_GRAPHS, 128, 0, stream>>>(emb, cnt, linW, linb, out);
}

// Round 5
// 354.657 us; speedup vs baseline: 1.8900x; 1.0133x over previous
//
#include <hip/hip_runtime.h>

#define N_NODES 50000
#define HIDDEN 128
#define NUM_GRAPHS 64
#define NUM_CLASSES 6
#define SCAN_NB ((N_NODES + 255) / 256)   // 196
#define N_PAD 50048                       // N rounded up to 64

typedef __attribute__((ext_vector_type(8))) short short8;
typedef __attribute__((ext_vector_type(4))) float float4v;

__device__ __forceinline__ float b2f(unsigned short u) {
    return __uint_as_float(((unsigned)u) << 16);
}
__device__ __forceinline__ unsigned short f2b(float f) {
    unsigned u = __float_as_uint(f);
    return (unsigned short)((u + 0x7FFFu + ((u >> 16) & 1u)) >> 16);
}

// ---------------- degree ----------------
__global__ void count_deg(const int* __restrict__ dst, int* deg, int e) {
    int i = blockIdx.x * 256 + threadIdx.x;
    if (i < e) atomicAdd(&deg[dst[i]], 1);
}

// ---------------- scan phase 1: block sums (+ dinv fold) ----------------
__global__ __launch_bounds__(256) void scan_b1(const int* __restrict__ deg, int* partial,
                                               float* __restrict__ dinv, int n) {
    __shared__ int red[4];
    const int t = threadIdx.x;
    const int i = blockIdx.x * 256 + t;
    int dv = (i < n) ? (deg[i] + 1) : 0;
    if (i < n) dinv[i] = rsqrtf((float)dv);
    int v = dv;
    for (int d = 32; d > 0; d >>= 1) v += __shfl_down(v, d, 64);
    if ((t & 63) == 0) red[t >> 6] = v;
    __syncthreads();
    if (t == 0) partial[blockIdx.x] = red[0] + red[1] + red[2] + red[3];
}

__global__ __launch_bounds__(256) void scan_b2(int* partial, int* off_n, int nb) {
    __shared__ int s[256];
    const int t = threadIdx.x;
    int v = (t < nb) ? partial[t] : 0;
    s[t] = v;
    __syncthreads();
    for (int d = 1; d < 256; d <<= 1) {
        int u = (t >= d) ? s[t - d] : 0;
        __syncthreads();
        s[t] += u;
        __syncthreads();
    }
    if (t < nb) partial[t] = s[t];
    if (t == nb - 1) *off_n = s[t];
}

// ---------------- scan phase 3 (+ fill_self + cursor seed fold) ----------------
__global__ __launch_bounds__(256) void scan_b3(const int* __restrict__ deg, const int* __restrict__ partial,
                                               int* off, int* cursor, int2* __restrict__ csr, int n) {
    __shared__ int s[256];
    const int t = threadIdx.x;
    const int b = blockIdx.x;
    const int i = b * 256 + t;
    int v = (i < n) ? (deg[i] + 1) : 0;
    s[t] = v;
    __syncthreads();
    for (int d = 1; d < 256; d <<= 1) {
        int u = (t >= d) ? s[t - d] : 0;
        __syncthreads();
        s[t] += u;
        __syncthreads();
    }
    int base = (b == 0) ? 0 : partial[b - 1];
    if (i < n) {
        int pos = base + s[t] - v;       // exclusive scan
        off[i] = pos;
        cursor[i] = pos + 1;             // edges go after the self entry
        // self-loop entry: col=i, val = dinv[i]^2 = 1/(deg+1) exactly
        csr[pos] = make_int2(i, __float_as_int(1.0f / (float)v));
    }
}

// ---------------- CSR fill (edges) ----------------
__global__ void fill_edge(const int* __restrict__ src, const int* __restrict__ dst,
                          const float* __restrict__ dinv,
                          int* cursor, int2* __restrict__ csr, int e) {
    int i = blockIdx.x * 256 + threadIdx.x;
    if (i >= e) return;
    int s = src[i], d = dst[i];
    int pos = atomicAdd(&cursor[d], 1);
    csr[pos] = make_int2(s, __float_as_int(dinv[s] * dinv[d]));
}

// ---------------- cast x f32 -> bf16 ----------------
__global__ void cast_x(const float* __restrict__ x, unsigned short* __restrict__ xb, int total) {
    int i = (blockIdx.x * 256 + threadIdx.x) * 4;
    if (i >= total) return;
    float4 v = *(const float4*)&x[i];
    ushort4 o;
    o.x = f2b(v.x); o.y = f2b(v.y); o.z = f2b(v.z); o.w = f2b(v.w);
    *(ushort4*)&xb[i] = o;
}

// ---------------- convert W0/W1/W2 into MFMA-B fragment order, bf16 ----------------
__global__ void conv_w(const float* __restrict__ W0, const float* __restrict__ W1,
                       const float* __restrict__ W2, unsigned short* __restrict__ wb) {
    int i = blockIdx.x * 256 + threadIdx.x;
    if (i >= 3 * 16384) return;
    int wsel = i >> 14;
    int r = i & 16383;
    int j = r & 7;
    int lane = (r >> 3) & 63;
    int f = r >> 9;               // 0..31
    int ki = f >> 3, nt = f & 7;
    int k = ki * 32 + (lane >> 4) * 8 + j;
    int c = nt * 16 + (lane & 15);
    const float* W = (wsel == 0) ? W0 : ((wsel == 1) ? W1 : W2);
    wb[i] = f2b(W[k * 128 + c]);
}

// ---------------- aggregation: t[d] = sum_p val[p]*h[col[p]] ----------------
__global__ __launch_bounds__(256) void agg_bf16(const unsigned short* __restrict__ hb, const int* __restrict__ off,
                                                const int2* __restrict__ csr,
                                                unsigned short* __restrict__ tb, int n) {
    const int wave = threadIdx.x >> 6;
    const int lane = threadIdx.x & 63;
    const int node = blockIdx.x * 4 + wave;
    if (node >= n) return;
    const int p0 = off[node], p1 = off[node + 1];
    const int grp = lane >> 4;      // 0..3: edge-in-chunk group
    const int fl = lane & 15;       // features fl*8 .. fl*8+7

    float acc[8];
#pragma unroll
    for (int j = 0; j < 8; j++) acc[j] = 0.f;

    for (int base = p0; base < p1; base += 64) {
        const int nb = min(64, p1 - base);
        int2 cv = make_int2(0, 0);
        if (lane < nb) cv = csr[base + lane];
        int myc = cv.x;
        float myv = __int_as_float(cv.y);
        for (int c0 = 0; c0 < nb; c0 += 4) {
            const int e = c0 + grp;
            const int cc = __shfl(myc, e, 64);
            const float vv = __shfl(myv, e, 64);
            if (e < nb) {
                short8 u = *(const short8*)&hb[cc * 128 + fl * 8];
#pragma unroll
                for (int j = 0; j < 8; j++) acc[j] += vv * b2f((unsigned short)u[j]);
            }
        }
    }

#pragma unroll
    for (int j = 0; j < 8; j++) {
        acc[j] += __shfl_xor(acc[j], 16, 64);
        acc[j] += __shfl_xor(acc[j], 32, 64);
    }

    if (grp == 0) {
        short8 o;
#pragma unroll
        for (int j = 0; j < 8; j++) o[j] = (short)f2b(acc[j]);
        *(short8*)&tb[node * 128 + fl * 8] = o;
    }
}

// ---------------- GEMM: h = relu(t @ W + b), bf16 MFMA, f32 accum ----------------
__global__ __launch_bounds__(256) void gemm_mfma(const unsigned short* __restrict__ tb,
                                                 const unsigned short* __restrict__ wb,
                                                 const float* __restrict__ bias,
                                                 unsigned short* __restrict__ hout, int n) {
    const int lane = threadIdx.x & 63;
    const int wave = threadIdx.x >> 6;
    const int r0 = blockIdx.x * 64 + wave * 16;
    const int m = lane & 15;
    const int quad = lane >> 4;
    const short* A = (const short*)tb;
    const short* B = (const short*)wb;

    float4v acc[8];
#pragma unroll
    for (int nt = 0; nt < 8; nt++) acc[nt] = (float4v){0.f, 0.f, 0.f, 0.f};

#pragma unroll
    for (int ki = 0; ki < 4; ki++) {
        short8 a = *(const short8*)&A[(r0 + m) * 128 + ki * 32 + quad * 8];
#pragma unroll
        for (int nt = 0; nt < 8; nt++) {
            short8 b = *(const short8*)&B[((ki * 8 + nt) * 64 + lane) * 8];
            acc[nt] = __builtin_amdgcn_mfma_f32_16x16x32_bf16(a, b, acc[nt], 0, 0, 0);
        }
    }

#pragma unroll
    for (int nt = 0; nt < 8; nt++) {
        int c = nt * 16 + m;
        float bv = bias[c];
#pragma unroll
        for (int reg = 0; reg < 4; reg++) {
            int row = r0 + quad * 4 + reg;
            if (row < n) {
                float v = fmaxf(acc[nt][reg] + bv, 0.f);
                hout[row * 128 + c] = f2b(v);
            }
        }
    }
}

// ---------------- pooling (batch sorted), bf16 input ----------------
__global__ __launch_bounds__(128) void pool_kernel(const unsigned short* __restrict__ h, const int* __restrict__ batch,
                                                   float* emb, int* cnt, int n) {
    const int f = threadIdx.x;        // 0..127
    const int n0 = blockIdx.x * 64;
    const int n1 = min(n0 + 64, n);
    float s = 0.f;
    int cloc = 0;
    int curg = batch[n0];
    for (int nn = n0; nn < n1; nn++) {
        int g = batch[nn];
        if (g != curg) {
            atomicAdd(&emb[curg * HIDDEN + f], s);
            if (f == 0) atomicAdd(&cnt[curg], cloc);
            s = 0.f;
            cloc = 0;
            curg = g;
        }
        s += b2f(h[nn * HIDDEN + f]);
        cloc++;
    }
    atomicAdd(&emb[curg * HIDDEN + f], s);
    if (f == 0) atomicAdd(&cnt[curg], cloc);
}

// ---------------- finalize ----------------
__global__ __launch_bounds__(128) void finalize_kernel(const float* __restrict__ emb, const int* __restrict__ cnt,
                                                       const float* __restrict__ linW, const float* __restrict__ linb,
                                                       float* out) {
    const int g = blockIdx.x;
    const int f = threadIdx.x;
    __shared__ float es[128];
    float c = (float)max(cnt[g], 1);
    float e = emb[g * HIDDEN + f] / c;
    out[NUM_GRAPHS * NUM_CLASSES + g * HIDDEN + f] = e;
    es[f] = e;
    __syncthreads();
    if (f < NUM_CLASSES) {
        float s = linb[f];
        for (int k = 0; k < HIDDEN; k++) s += es[k] * linW[k * NUM_CLASSES + f];
        out[g * NUM_CLASSES + f] = s;
    }
}

extern "C" void kernel_launch(void* const* d_in, const int* in_sizes, int n_in,
                              void* d_out, int out_size, void* d_ws, size_t ws_size,
                              hipStream_t stream) {
    const float* x    = (const float*)d_in[0];
    const int*   ei   = (const int*)d_in[1];
    const int*   batch= (const int*)d_in[2];
    const float* W0   = (const float*)d_in[3];
    const float* b0   = (const float*)d_in[4];
    const float* W1   = (const float*)d_in[5];
    const float* b1   = (const float*)d_in[6];
    const float* W2   = (const float*)d_in[7];
    const float* b2   = (const float*)d_in[8];
    const float* linW = (const float*)d_in[9];
    const float* linb = (const float*)d_in[10];
    float* out = (float*)d_out;

    const int N = N_NODES;
    const int E = in_sizes[1] / 2;
    const int M = E + N;
    const int* srcp = ei;
    const int* dstp = ei + E;

    char* w = (char*)d_ws;
    size_t o = 0;
    auto alloc = [&](size_t bytes) { size_t r = o; o += (bytes + 255) & ~(size_t)255; return r; };
    int*            off_i   = (int*)           (w + alloc((size_t)(N + 1) * 4));
    int*            cursor  = (int*)           (w + alloc((size_t)N * 4));
    int*            deg     = (int*)           (w + alloc((size_t)N * 4));
    float*          dinv    = (float*)         (w + alloc((size_t)N * 4));
    int*            partial = (int*)           (w + alloc((size_t)SCAN_NB * 4));
    int2*           csr     = (int2*)          (w + alloc((size_t)M * 8));
    unsigned short* xb      = (unsigned short*)(w + alloc((size_t)N_PAD * HIDDEN * 2));
    unsigned short* tb      = (unsigned short*)(w + alloc((size_t)N_PAD * HIDDEN * 2));
    unsigned short* hb      = (unsigned short*)(w + alloc((size_t)N_PAD * HIDDEN * 2));
    unsigned short* wb      = (unsigned short*)(w + alloc((size_t)3 * 16384 * 2));
    float*          emb     = (float*)         (w + alloc((size_t)NUM_GRAPHS * HIDDEN * 4));
    int*            cnt     = (int*)           (w + alloc((size_t)NUM_GRAPHS * 4));

    hipMemsetAsync(deg, 0, (size_t)N * 4, stream);
    hipMemsetAsync(emb, 0, (size_t)(NUM_GRAPHS * HIDDEN * 4 + 256 + NUM_GRAPHS * 4), stream); // emb + pad + cnt

    cast_x<<<(N * HIDDEN / 4 + 255) / 256, 256, 0, stream>>>(x, xb, N * HIDDEN);
    conv_w<<<(3 * 16384 + 255) / 256, 256, 0, stream>>>(W0, W1, W2, wb);

    count_deg<<<(E + 255) / 256, 256, 0, stream>>>(dstp, deg, E);

    scan_b1<<<SCAN_NB, 256, 0, stream>>>(deg, partial, dinv, N);
    scan_b2<<<1, 256, 0, stream>>>(partial, off_i + N, SCAN_NB);
    scan_b3<<<SCAN_NB, 256, 0, stream>>>(deg, partial, off_i, cursor, csr, N);

    fill_edge<<<(E + 255) / 256, 256, 0, stream>>>(srcp, dstp, dinv, cursor, csr, E);

    const int gemm_grid = (N + 63) / 64;   // 782
    const int agg_grid  = (N + 3) / 4;     // 12500

    agg_bf16<<<agg_grid, 256, 0, stream>>>(xb, off_i, csr, tb, N);
    gemm_mfma<<<gemm_grid, 256, 0, stream>>>(tb, wb + 0 * 16384, b0, hb, N);
    agg_bf16<<<agg_grid, 256, 0, stream>>>(hb, off_i, csr, tb, N);
    gemm_mfma<<<gemm_grid, 256, 0, stream>>>(tb, wb + 1 * 16384, b1, hb, N);
    agg_bf16<<<agg_grid, 256, 0, stream>>>(hb, off_i, csr, tb, N);
    gemm_mfma<<<gemm_grid, 256, 0, stream>>>(tb, wb + 2 * 16384, b2, hb, N);

    pool_kernel<<<(N + 63) / 64, 128, 0, stream>>>(hb, batch, emb, cnt, N);
    finalize_kernel<<<NUM_GRAPHS, 128, 0, stream>>>(emb, cnt, linW, linb, out);
}

// Round 6
// 326.591 us; speedup vs baseline: 2.0524x; 1.0859x over previous
//
#include <hip/hip_runtime.h>

#define N_NODES 50000
#define HIDDEN 128
#define NUM_GRAPHS 64
#define NUM_CLASSES 6
#define SCAN_NB ((N_NODES + 255) / 256)   // 196
#define N_PAD 50048                       // N rounded up to 64
#define DEG_STRIDE 16                     // one counter per 64B line

typedef __attribute__((ext_vector_type(8))) short short8;
typedef __attribute__((ext_vector_type(4))) float float4v;

__device__ __forceinline__ float b2f(unsigned short u) {
    return __uint_as_float(((unsigned)u) << 16);
}
__device__ __forceinline__ unsigned short f2b(float f) {
    unsigned u = __float_as_uint(f);
    return (unsigned short)((u + 0x7FFFu + ((u >> 16) & 1u)) >> 16);
}

// ---------------- degree + per-edge rank ----------------
__global__ void count_deg(const int* __restrict__ dst, int* __restrict__ deg,
                          int* __restrict__ rank, int e) {
    int i = blockIdx.x * 256 + threadIdx.x;
    if (i < e) rank[i] = atomicAdd(&deg[dst[i] * DEG_STRIDE], 1);
}

// ---------------- scan phase 1: block sums (+ dinv fold) ----------------
__global__ __launch_bounds__(256) void scan_b1(const int* __restrict__ deg, int* partial,
                                               float* __restrict__ dinv, int n) {
    __shared__ int red[4];
    const int t = threadIdx.x;
    const int i = blockIdx.x * 256 + t;
    int dv = (i < n) ? (deg[i * DEG_STRIDE] + 1) : 0;
    if (i < n) dinv[i] = rsqrtf((float)dv);
    int v = dv;
    for (int d = 32; d > 0; d >>= 1) v += __shfl_down(v, d, 64);
    if ((t & 63) == 0) red[t >> 6] = v;
    __syncthreads();
    if (t == 0) partial[blockIdx.x] = red[0] + red[1] + red[2] + red[3];
}

__global__ __launch_bounds__(256) void scan_b2(int* partial, int* off_n, int nb) {
    __shared__ int s[256];
    const int t = threadIdx.x;
    int v = (t < nb) ? partial[t] : 0;
    s[t] = v;
    __syncthreads();
    for (int d = 1; d < 256; d <<= 1) {
        int u = (t >= d) ? s[t - d] : 0;
        __syncthreads();
        s[t] += u;
        __syncthreads();
    }
    if (t < nb) partial[t] = s[t];
    if (t == nb - 1) *off_n = s[t];
}

// ---------------- scan phase 3 (+ self-entry fold) ----------------
__global__ __launch_bounds__(256) void scan_b3(const int* __restrict__ deg, const int* __restrict__ partial,
                                               int* off, int* __restrict__ csr_col, int n) {
    __shared__ int s[256];
    const int t = threadIdx.x;
    const int b = blockIdx.x;
    const int i = b * 256 + t;
    int v = (i < n) ? (deg[i * DEG_STRIDE] + 1) : 0;
    s[t] = v;
    __syncthreads();
    for (int d = 1; d < 256; d <<= 1) {
        int u = (t >= d) ? s[t - d] : 0;
        __syncthreads();
        s[t] += u;
        __syncthreads();
    }
    int base = (b == 0) ? 0 : partial[b - 1];
    if (i < n) {
        int pos = base + s[t] - v;       // exclusive scan
        off[i] = pos;
        csr_col[pos] = i;                // self-loop first in segment
    }
}

// ---------------- CSR fill (edges), atomic-free ----------------
__global__ void fill_edge(const int* __restrict__ src, const int* __restrict__ dst,
                          const int* __restrict__ rank, const int* __restrict__ off,
                          int* __restrict__ csr_col, int e) {
    int i = blockIdx.x * 256 + threadIdx.x;
    if (i >= e) return;
    int d = dst[i];
    int pos = off[d] + 1 + rank[i];
    csr_col[pos] = src[i];
}

// ---------------- cast x f32 -> bf16, pre-scaled by dinv[row] ----------------
__global__ void cast_x(const float* __restrict__ x, const float* __restrict__ dinv,
                       unsigned short* __restrict__ xs, int total) {
    int i = (blockIdx.x * 256 + threadIdx.x) * 4;
    if (i >= total) return;
    float sc = dinv[i >> 7];
    float4 v = *(const float4*)&x[i];
    ushort4 o;
    o.x = f2b(v.x * sc); o.y = f2b(v.y * sc); o.z = f2b(v.z * sc); o.w = f2b(v.w * sc);
    *(ushort4*)&xs[i] = o;
}

// ---------------- convert W0/W1/W2 into MFMA-B fragment order, bf16 ----------------
__global__ void conv_w(const float* __restrict__ W0, const float* __restrict__ W1,
                       const float* __restrict__ W2, unsigned short* __restrict__ wb) {
    int i = blockIdx.x * 256 + threadIdx.x;
    if (i >= 3 * 16384) return;
    int wsel = i >> 14;
    int r = i & 16383;
    int j = r & 7;
    int lane = (r >> 3) & 63;
    int f = r >> 9;               // 0..31
    int ki = f >> 3, nt = f & 7;
    int k = ki * 32 + (lane >> 4) * 8 + j;
    int c = nt * 16 + (lane & 15);
    const float* W = (wsel == 0) ? W0 : ((wsel == 1) ? W1 : W2);
    wb[i] = f2b(W[k * 128 + c]);
}

// ---------------- aggregation: t[d] = dinv[d] * sum_p hs[col[p]] ----------------
__global__ __launch_bounds__(256) void agg_bf16(const unsigned short* __restrict__ hs, const int* __restrict__ off,
                                                const int* __restrict__ csr_col, const float* __restrict__ dinv,
                                                unsigned short* __restrict__ tb, int n) {
    const int wave = threadIdx.x >> 6;
    const int lane = threadIdx.x & 63;
    const int node = blockIdx.x * 4 + wave;
    if (node >= n) return;
    const int p0 = off[node], p1 = off[node + 1];
    const int grp = lane >> 4;      // 0..3: edge-in-chunk group
    const int fl = lane & 15;       // features fl*8 .. fl*8+7

    float acc[8];
#pragma unroll
    for (int j = 0; j < 8; j++) acc[j] = 0.f;

    for (int base = p0; base < p1; base += 64) {
        const int nb = min(64, p1 - base);
        int myc = (lane < nb) ? csr_col[base + lane] : 0;
        for (int c0 = 0; c0 < nb; c0 += 4) {
            const int e = c0 + grp;
            const int cc = __shfl(myc, e, 64);
            if (e < nb) {
                short8 u = *(const short8*)&hs[cc * 128 + fl * 8];
#pragma unroll
                for (int j = 0; j < 8; j++) acc[j] += b2f((unsigned short)u[j]);
            }
        }
    }

#pragma unroll
    for (int j = 0; j < 8; j++) {
        acc[j] += __shfl_xor(acc[j], 16, 64);
        acc[j] += __shfl_xor(acc[j], 32, 64);
    }

    if (grp == 0) {
        const float dv = dinv[node];
        short8 o;
#pragma unroll
        for (int j = 0; j < 8; j++) o[j] = (short)f2b(acc[j] * dv);
        *(short8*)&tb[node * 128 + fl * 8] = o;
    }
}

// ---------------- GEMM: out = [rowscale*] relu(t @ W + b), bf16 MFMA ----------------
__global__ __launch_bounds__(256) void gemm_mfma(const unsigned short* __restrict__ tb,
                                                 const unsigned short* __restrict__ wb,
                                                 const float* __restrict__ bias,
                                                 const float* __restrict__ rowscale,
                                                 unsigned short* __restrict__ hout, int n) {
    const int lane = threadIdx.x & 63;
    const int wave = threadIdx.x >> 6;
    const int r0 = blockIdx.x * 64 + wave * 16;
    const int m = lane & 15;
    const int quad = lane >> 4;
    const short* A = (const short*)tb;
    const short* B = (const short*)wb;

    float4v acc[8];
#pragma unroll
    for (int nt = 0; nt < 8; nt++) acc[nt] = (float4v){0.f, 0.f, 0.f, 0.f};

#pragma unroll
    for (int ki = 0; ki < 4; ki++) {
        short8 a = *(const short8*)&A[(r0 + m) * 128 + ki * 32 + quad * 8];
#pragma unroll
        for (int nt = 0; nt < 8; nt++) {
            short8 b = *(const short8*)&B[((ki * 8 + nt) * 64 + lane) * 8];
            acc[nt] = __builtin_amdgcn_mfma_f32_16x16x32_bf16(a, b, acc[nt], 0, 0, 0);
        }
    }

    float sc[4];
#pragma unroll
    for (int reg = 0; reg < 4; reg++) {
        int row = r0 + quad * 4 + reg;
        sc[reg] = (rowscale && row < n) ? rowscale[row] : 1.f;
    }

#pragma unroll
    for (int nt = 0; nt < 8; nt++) {
        int c = nt * 16 + m;
        float bv = bias[c];
#pragma unroll
        for (int reg = 0; reg < 4; reg++) {
            int row = r0 + quad * 4 + reg;
            if (row < n) {
                float v = fmaxf(acc[nt][reg] + bv, 0.f) * sc[reg];
                hout[row * 128 + c] = f2b(v);
            }
        }
    }
}

// ---------------- pooling (batch sorted), bf16 input ----------------
__global__ __launch_bounds__(128) void pool_kernel(const unsigned short* __restrict__ h, const int* __restrict__ batch,
                                                   float* emb, int* cnt, int n) {
    const int f = threadIdx.x;        // 0..127
    const int n0 = blockIdx.x * 64;
    const int n1 = min(n0 + 64, n);
    float s = 0.f;
    int cloc = 0;
    int curg = batch[n0];
    for (int nn = n0; nn < n1; nn++) {
        int g = batch[nn];
        if (g != curg) {
            atomicAdd(&emb[curg * HIDDEN + f], s);
            if (f == 0) atomicAdd(&cnt[curg], cloc);
            s = 0.f;
            cloc = 0;
            curg = g;
        }
        s += b2f(h[nn * HIDDEN + f]);
        cloc++;
    }
    atomicAdd(&emb[curg * HIDDEN + f], s);
    if (f == 0) atomicAdd(&cnt[curg], cloc);
}

// ---------------- finalize ----------------
__global__ __launch_bounds__(128) void finalize_kernel(const float* __restrict__ emb, const int* __restrict__ cnt,
                                                       const float* __restrict__ linW, const float* __restrict__ linb,
                                                       float* out) {
    const int g = blockIdx.x;
    const int f = threadIdx.x;
    __shared__ float es[128];
    float c = (float)max(cnt[g], 1);
    float e = emb[g * HIDDEN + f] / c;
    out[NUM_GRAPHS * NUM_CLASSES + g * HIDDEN + f] = e;
    es[f] = e;
    __syncthreads();
    if (f < NUM_CLASSES) {
        float s = linb[f];
        for (int k = 0; k < HIDDEN; k++) s += es[k] * linW[k * NUM_CLASSES + f];
        out[g * NUM_CLASSES + f] = s;
    }
}

extern "C" void kernel_launch(void* const* d_in, const int* in_sizes, int n_in,
                              void* d_out, int out_size, void* d_ws, size_t ws_size,
                              hipStream_t stream) {
    const float* x    = (const float*)d_in[0];
    const int*   ei   = (const int*)d_in[1];
    const int*   batch= (const int*)d_in[2];
    const float* W0   = (const float*)d_in[3];
    const float* b0   = (const float*)d_in[4];
    const float* W1   = (const float*)d_in[5];
    const float* b1   = (const float*)d_in[6];
    const float* W2   = (const float*)d_in[7];
    const float* b2   = (const float*)d_in[8];
    const float* linW = (const float*)d_in[9];
    const float* linb = (const float*)d_in[10];
    float* out = (float*)d_out;

    const int N = N_NODES;
    const int E = in_sizes[1] / 2;
    const int M = E + N;
    const int* srcp = ei;
    const int* dstp = ei + E;

    char* w = (char*)d_ws;
    size_t o = 0;
    auto alloc = [&](size_t bytes) { size_t r = o; o += (bytes + 255) & ~(size_t)255; return r; };
    int*            off_i   = (int*)           (w + alloc((size_t)(N + 1) * 4));
    int*            deg     = (int*)           (w + alloc((size_t)N * DEG_STRIDE * 4));
    float*          dinv    = (float*)         (w + alloc((size_t)N * 4));
    int*            partial = (int*)           (w + alloc((size_t)SCAN_NB * 4));
    int*            rank    = (int*)           (w + alloc((size_t)E * 4));
    int*            csr_col = (int*)           (w + alloc((size_t)M * 4));
    unsigned short* xs      = (unsigned short*)(w + alloc((size_t)N_PAD * HIDDEN * 2));
    unsigned short* tb      = (unsigned short*)(w + alloc((size_t)N_PAD * HIDDEN * 2));
    unsigned short* hb      = (unsigned short*)(w + alloc((size_t)N_PAD * HIDDEN * 2));
    unsigned short* wb      = (unsigned short*)(w + alloc((size_t)3 * 16384 * 2));
    float*          emb     = (float*)         (w + alloc((size_t)NUM_GRAPHS * HIDDEN * 4));
    int*            cnt     = (int*)           (w + alloc((size_t)NUM_GRAPHS * 4));

    hipMemsetAsync(deg, 0, (size_t)N * DEG_STRIDE * 4, stream);
    hipMemsetAsync(emb, 0, (size_t)(NUM_GRAPHS * HIDDEN * 4 + 256 + NUM_GRAPHS * 4), stream); // emb + pad + cnt

    conv_w<<<(3 * 16384 + 255) / 256, 256, 0, stream>>>(W0, W1, W2, wb);

    count_deg<<<(E + 255) / 256, 256, 0, stream>>>(dstp, deg, rank, E);

    scan_b1<<<SCAN_NB, 256, 0, stream>>>(deg, partial, dinv, N);
    scan_b2<<<1, 256, 0, stream>>>(partial, off_i + N, SCAN_NB);
    scan_b3<<<SCAN_NB, 256, 0, stream>>>(deg, partial, off_i, csr_col, N);

    cast_x<<<(N * HIDDEN / 4 + 255) / 256, 256, 0, stream>>>(x, dinv, xs, N * HIDDEN);
    fill_edge<<<(E + 255) / 256, 256, 0, stream>>>(srcp, dstp, rank, off_i, csr_col, E);

    const int gemm_grid = (N + 63) / 64;   // 782
    const int agg_grid  = (N + 3) / 4;     // 12500

    agg_bf16<<<agg_grid, 256, 0, stream>>>(xs, off_i, csr_col, dinv, tb, N);
    gemm_mfma<<<gemm_grid, 256, 0, stream>>>(tb, wb + 0 * 16384, b0, dinv, hb, N);
    agg_bf16<<<agg_grid, 256, 0, stream>>>(hb, off_i, csr_col, dinv, tb, N);
    gemm_mfma<<<gemm_grid, 256, 0, stream>>>(tb, wb + 1 * 16384, b1, dinv, hb, N);
    agg_bf16<<<agg_grid, 256, 0, stream>>>(hb, off_i, csr_col, dinv, tb, N);
    gemm_mfma<<<gemm_grid, 256, 0, stream>>>(tb, wb + 2 * 16384, b2, (const float*)nullptr, hb, N);

    pool_kernel<<<(N + 63) / 64, 128, 0, stream>>>(hb, batch, emb, cnt, N);
    finalize_kernel<<<NUM_GRAPHS, 128, 0, stream>>>(emb, cnt, linW, linb, out);
}

// Round 7
// 313.557 us; speedup vs baseline: 2.1377x; 1.0416x over previous
//
#include <hip/hip_runtime.h>

#define N_NODES 50000
#define HIDDEN 128
#define NUM_GRAPHS 64
#define NUM_CLASSES 6
#define SCAN_NB ((N_NODES + 255) / 256)   // 196
#define N_PAD 50048                       // N rounded up to 64
#define DEG_STRIDE 16                     // one counter per 64B line

typedef __attribute__((ext_vector_type(8))) short short8;
typedef __attribute__((ext_vector_type(4))) float float4v;

__device__ __forceinline__ float b2f(unsigned short u) {
    return __uint_as_float(((unsigned)u) << 16);
}
__device__ __forceinline__ unsigned short f2b(float f) {
    unsigned u = __float_as_uint(f);
    return (unsigned short)((u + 0x7FFFu + ((u >> 16) & 1u)) >> 16);
}

// ---------------- degree + per-edge rank ----------------
__global__ void count_deg(const int* __restrict__ dst, int* __restrict__ deg,
                          int* __restrict__ rank, int e) {
    int i = blockIdx.x * 256 + threadIdx.x;
    if (i < e) rank[i] = atomicAdd(&deg[dst[i] * DEG_STRIDE], 1);
}

// ---------------- scan phase 1: block sums (+ dinv fold) ----------------
__global__ __launch_bounds__(256) void scan_b1(const int* __restrict__ deg, int* partial,
                                               float* __restrict__ dinv, int n) {
    __shared__ int red[4];
    const int t = threadIdx.x;
    const int i = blockIdx.x * 256 + t;
    int dv = (i < n) ? (deg[i * DEG_STRIDE] + 1) : 0;
    if (i < n) dinv[i] = rsqrtf((float)dv);
    int v = dv;
    for (int d = 32; d > 0; d >>= 1) v += __shfl_down(v, d, 64);
    if ((t & 63) == 0) red[t >> 6] = v;
    __syncthreads();
    if (t == 0) partial[blockIdx.x] = red[0] + red[1] + red[2] + red[3];
}

__global__ __launch_bounds__(256) void scan_b2(int* partial, int* off_n, int nb) {
    __shared__ int s[256];
    const int t = threadIdx.x;
    int v = (t < nb) ? partial[t] : 0;
    s[t] = v;
    __syncthreads();
    for (int d = 1; d < 256; d <<= 1) {
        int u = (t >= d) ? s[t - d] : 0;
        __syncthreads();
        s[t] += u;
        __syncthreads();
    }
    if (t < nb) partial[t] = s[t];
    if (t == nb - 1) *off_n = s[t];
}

// ---------------- scan phase 3 (+ self-entry fold) ----------------
__global__ __launch_bounds__(256) void scan_b3(const int* __restrict__ deg, const int* __restrict__ partial,
                                               int* off, int* __restrict__ csr_col, int n) {
    __shared__ int s[256];
    const int t = threadIdx.x;
    const int b = blockIdx.x;
    const int i = b * 256 + t;
    int v = (i < n) ? (deg[i * DEG_STRIDE] + 1) : 0;
    s[t] = v;
    __syncthreads();
    for (int d = 1; d < 256; d <<= 1) {
        int u = (t >= d) ? s[t - d] : 0;
        __syncthreads();
        s[t] += u;
        __syncthreads();
    }
    int base = (b == 0) ? 0 : partial[b - 1];
    if (i < n) {
        int pos = base + s[t] - v;       // exclusive scan
        off[i] = pos;
        csr_col[pos] = i;                // self-loop first in segment
    }
}

// ---------------- CSR fill (edges), atomic-free ----------------
__global__ void fill_edge(const int* __restrict__ src, const int* __restrict__ dst,
                          const int* __restrict__ rank, const int* __restrict__ off,
                          int* __restrict__ csr_col, int e) {
    int i = blockIdx.x * 256 + threadIdx.x;
    if (i >= e) return;
    int d = dst[i];
    int pos = off[d] + 1 + rank[i];
    csr_col[pos] = src[i];
}

// ---------------- cast x f32 -> bf16, pre-scaled by dinv[row] ----------------
__global__ void cast_x(const float* __restrict__ x, const float* __restrict__ dinv,
                       unsigned short* __restrict__ xs, int total) {
    int i = (blockIdx.x * 256 + threadIdx.x) * 4;
    if (i >= total) return;
    float sc = dinv[i >> 7];
    float4 v = *(const float4*)&x[i];
    ushort4 o;
    o.x = f2b(v.x * sc); o.y = f2b(v.y * sc); o.z = f2b(v.z * sc); o.w = f2b(v.w * sc);
    *(ushort4*)&xs[i] = o;
}

// ---------------- convert W0/W1/W2 into MFMA-B fragment order, bf16 ----------------
__global__ void conv_w(const float* __restrict__ W0, const float* __restrict__ W1,
                       const float* __restrict__ W2, unsigned short* __restrict__ wb) {
    int i = blockIdx.x * 256 + threadIdx.x;
    if (i >= 3 * 16384) return;
    int wsel = i >> 14;
    int r = i & 16383;
    int j = r & 7;
    int lane = (r >> 3) & 63;
    int f = r >> 9;               // 0..31
    int ki = f >> 3, nt = f & 7;
    int k = ki * 32 + (lane >> 4) * 8 + j;
    int c = nt * 16 + (lane & 15);
    const float* W = (wsel == 0) ? W0 : ((wsel == 1) ? W1 : W2);
    wb[i] = f2b(W[k * 128 + c]);
}

// ---------------- aggregation: t[d] = dinv[d] * sum_p hs[col[p]] ----------------
// wave/node; 4 lane-groups; 16 edges per inner iter = 4 independent gathers in flight per lane
__global__ __launch_bounds__(256) void agg_bf16(const unsigned short* __restrict__ hs, const int* __restrict__ off,
                                                const int* __restrict__ csr_col, const float* __restrict__ dinv,
                                                unsigned short* __restrict__ tb, int n) {
    const int wave = threadIdx.x >> 6;
    const int lane = threadIdx.x & 63;
    const int node = blockIdx.x * 4 + wave;
    if (node >= n) return;
    const int p0 = off[node], p1 = off[node + 1];
    const int grp = lane >> 4;      // 0..3: edge-in-chunk group
    const int fl = lane & 15;       // features fl*8 .. fl*8+7

    float acc[8];
#pragma unroll
    for (int j = 0; j < 8; j++) acc[j] = 0.f;

    for (int base = p0; base < p1; base += 64) {
        const int nb = min(64, p1 - base);
        const int nbm1 = nb - 1;
        int myc = (lane < nb) ? csr_col[base + lane] : 0;
        for (int c0 = 0; c0 < nb; c0 += 16) {
            int cc[4];
            float m[4];
#pragma unroll
            for (int k = 0; k < 4; k++) {
                int e = c0 + k * 4 + grp;
                m[k] = (e < nb) ? 1.f : 0.f;
                cc[k] = __shfl(myc, min(e, nbm1), 64);
            }
            short8 u[4];
#pragma unroll
            for (int k = 0; k < 4; k++)
                u[k] = *(const short8*)&hs[cc[k] * 128 + fl * 8];
#pragma unroll
            for (int k = 0; k < 4; k++)
#pragma unroll
                for (int j = 0; j < 8; j++)
                    acc[j] += m[k] * b2f((unsigned short)u[k][j]);
        }
    }

#pragma unroll
    for (int j = 0; j < 8; j++) {
        acc[j] += __shfl_xor(acc[j], 16, 64);
        acc[j] += __shfl_xor(acc[j], 32, 64);
    }

    if (grp == 0) {
        const float dv = dinv[node];
        short8 o;
#pragma unroll
        for (int j = 0; j < 8; j++) o[j] = (short)f2b(acc[j] * dv);
        *(short8*)&tb[node * 128 + fl * 8] = o;
    }
}

// ---------------- GEMM: out = [rowscale*] relu(t @ W + b), bf16 MFMA ----------------
__global__ __launch_bounds__(256) void gemm_mfma(const unsigned short* __restrict__ tb,
                                                 const unsigned short* __restrict__ wb,
                                                 const float* __restrict__ bias,
                                                 const float* __restrict__ rowscale,
                                                 unsigned short* __restrict__ hout, int n) {
    const int lane = threadIdx.x & 63;
    const int wave = threadIdx.x >> 6;
    const int r0 = blockIdx.x * 64 + wave * 16;
    const int m = lane & 15;
    const int quad = lane >> 4;
    const short* A = (const short*)tb;
    const short* B = (const short*)wb;

    float4v acc[8];
#pragma unroll
    for (int nt = 0; nt < 8; nt++) acc[nt] = (float4v){0.f, 0.f, 0.f, 0.f};

#pragma unroll
    for (int ki = 0; ki < 4; ki++) {
        short8 a = *(const short8*)&A[(r0 + m) * 128 + ki * 32 + quad * 8];
#pragma unroll
        for (int nt = 0; nt < 8; nt++) {
            short8 b = *(const short8*)&B[((ki * 8 + nt) * 64 + lane) * 8];
            acc[nt] = __builtin_amdgcn_mfma_f32_16x16x32_bf16(a, b, acc[nt], 0, 0, 0);
        }
    }

    float sc[4];
#pragma unroll
    for (int reg = 0; reg < 4; reg++) {
        int row = r0 + quad * 4 + reg;
        sc[reg] = (rowscale && row < n) ? rowscale[row] : 1.f;
    }

#pragma unroll
    for (int nt = 0; nt < 8; nt++) {
        int c = nt * 16 + m;
        float bv = bias[c];
#pragma unroll
        for (int reg = 0; reg < 4; reg++) {
            int row = r0 + quad * 4 + reg;
            if (row < n) {
                float v = fmaxf(acc[nt][reg] + bv, 0.f) * sc[reg];
                hout[row * 128 + c] = f2b(v);
            }
        }
    }
}

// ---------------- pooling (batch sorted), bf16 input ----------------
__global__ __launch_bounds__(128) void pool_kernel(const unsigned short* __restrict__ h, const int* __restrict__ batch,
                                                   float* emb, int* cnt, int n) {
    const int f = threadIdx.x;        // 0..127
    const int n0 = blockIdx.x * 64;
    const int n1 = min(n0 + 64, n);
    float s = 0.f;
    int cloc = 0;
    int curg = batch[n0];
    for (int nn = n0; nn < n1; nn++) {
        int g = batch[nn];
        if (g != curg) {
            atomicAdd(&emb[curg * HIDDEN + f], s);
            if (f == 0) atomicAdd(&cnt[curg], cloc);
            s = 0.f;
            cloc = 0;
            curg = g;
        }
        s += b2f(h[nn * HIDDEN + f]);
        cloc++;
    }
    atomicAdd(&emb[curg * HIDDEN + f], s);
    if (f == 0) atomicAdd(&cnt[curg], cloc);
}

// ---------------- finalize ----------------
__global__ __launch_bounds__(128) void finalize_kernel(const float* __restrict__ emb, const int* __restrict__ cnt,
                                                       const float* __restrict__ linW, const float* __restrict__ linb,
                                                       float* out) {
    const int g = blockIdx.x;
    const int f = threadIdx.x;
    __shared__ float es[128];
    float c = (float)max(cnt[g], 1);
    float e = emb[g * HIDDEN + f] / c;
    out[NUM_GRAPHS * NUM_CLASSES + g * HIDDEN + f] = e;
    es[f] = e;
    __syncthreads();
    if (f < NUM_CLASSES) {
        float s = linb[f];
        for (int k = 0; k < HIDDEN; k++) s += es[k] * linW[k * NUM_CLASSES + f];
        out[g * NUM_CLASSES + f] = s;
    }
}

extern "C" void kernel_launch(void* const* d_in, const int* in_sizes, int n_in,
                              void* d_out, int out_size, void* d_ws, size_t ws_size,
                              hipStream_t stream) {
    const float* x    = (const float*)d_in[0];
    const int*   ei   = (const int*)d_in[1];
    const int*   batch= (const int*)d_in[2];
    const float* W0   = (const float*)d_in[3];
    const float* b0   = (const float*)d_in[4];
    const float* W1   = (const float*)d_in[5];
    const float* b1   = (const float*)d_in[6];
    const float* W2   = (const float*)d_in[7];
    const float* b2   = (const float*)d_in[8];
    const float* linW = (const float*)d_in[9];
    const float* linb = (const float*)d_in[10];
    float* out = (float*)d_out;

    const int N = N_NODES;
    const int E = in_sizes[1] / 2;
    const int M = E + N;
    const int* srcp = ei;
    const int* dstp = ei + E;

    char* w = (char*)d_ws;
    size_t o = 0;
    auto alloc = [&](size_t bytes) { size_t r = o; o += (bytes + 255) & ~(size_t)255; return r; };
    int*            off_i   = (int*)           (w + alloc((size_t)(N + 1) * 4));
    int*            deg     = (int*)           (w + alloc((size_t)N * DEG_STRIDE * 4));
    float*          dinv    = (float*)         (w + alloc((size_t)N * 4));
    int*            partial = (int*)           (w + alloc((size_t)SCAN_NB * 4));
    int*            rank    = (int*)           (w + alloc((size_t)E * 4));
    int*            csr_col = (int*)           (w + alloc((size_t)M * 4));
    unsigned short* xs      = (unsigned short*)(w + alloc((size_t)N_PAD * HIDDEN * 2));
    unsigned short* tb      = (unsigned short*)(w + alloc((size_t)N_PAD * HIDDEN * 2));
    unsigned short* hb      = (unsigned short*)(w + alloc((size_t)N_PAD * HIDDEN * 2));
    unsigned short* wb      = (unsigned short*)(w + alloc((size_t)3 * 16384 * 2));
    float*          emb     = (float*)         (w + alloc((size_t)NUM_GRAPHS * HIDDEN * 4));
    int*            cnt     = (int*)           (w + alloc((size_t)NUM_GRAPHS * 4));

    hipMemsetAsync(deg, 0, (size_t)N * DEG_STRIDE * 4, stream);
    hipMemsetAsync(emb, 0, (size_t)(NUM_GRAPHS * HIDDEN * 4 + 256 + NUM_GRAPHS * 4), stream); // emb + pad + cnt

    conv_w<<<(3 * 16384 + 255) / 256, 256, 0, stream>>>(W0, W1, W2, wb);

    count_deg<<<(E + 255) / 256, 256, 0, stream>>>(dstp, deg, rank, E);

    scan_b1<<<SCAN_NB, 256, 0, stream>>>(deg, partial, dinv, N);
    scan_b2<<<1, 256, 0, stream>>>(partial, off_i + N, SCAN_NB);
    scan_b3<<<SCAN_NB, 256, 0, stream>>>(deg, partial, off_i, csr_col, N);

    cast_x<<<(N * HIDDEN / 4 + 255) / 256, 256, 0, stream>>>(x, dinv, xs, N * HIDDEN);
    fill_edge<<<(E + 255) / 256, 256, 0, stream>>>(srcp, dstp, rank, off_i, csr_col, E);

    const int gemm_grid = (N + 63) / 64;   // 782
    const int agg_grid  = (N + 3) / 4;     // 12500

    agg_bf16<<<agg_grid, 256, 0, stream>>>(xs, off_i, csr_col, dinv, tb, N);
    gemm_mfma<<<gemm_grid, 256, 0, stream>>>(tb, wb + 0 * 16384, b0, dinv, hb, N);
    agg_bf16<<<agg_grid, 256, 0, stream>>>(hb, off_i, csr_col, dinv, tb, N);
    gemm_mfma<<<gemm_grid, 256, 0, stream>>>(tb, wb + 1 * 16384, b1, dinv, hb, N);
    agg_bf16<<<agg_grid, 256, 0, stream>>>(hb, off_i, csr_col, dinv, tb, N);
    gemm_mfma<<<gemm_grid, 256, 0, stream>>>(tb, wb + 2 * 16384, b2, (const float*)nullptr, hb, N);

    pool_kernel<<<(N + 63) / 64, 128, 0, stream>>>(hb, batch, emb, cnt, N);
    finalize_kernel<<<NUM_GRAPHS, 128, 0, stream>>>(emb, cnt, linW, linb, out);
}